// Round 1
// 580.071 us; speedup vs baseline: 1.0537x; 1.0537x over previous
//
#include <hip/hip_runtime.h>

typedef unsigned short u16;
typedef __attribute__((ext_vector_type(8))) short short8;
typedef __attribute__((ext_vector_type(4))) short short4v;
typedef __attribute__((ext_vector_type(4))) float f32x4;

#define DEV static __device__ __forceinline__

DEV float bf2f(u16 h) {
    union { unsigned int u; float f; } v; v.u = ((unsigned int)h) << 16; return v.f;
}
DEV u16 f2bf(float f) {
    union { float f; unsigned int u; } v; v.f = f;
    unsigned int r = (v.u + 0x7fff + ((v.u >> 16) & 1)) >> 16;
    return (u16)r;
}
DEV float ldx(const void* p, size_t i, int f32) {
    return f32 ? ((const float*)p)[i] : bf2f(((const u16*)p)[i]);
}

#define GLD16(g, l) __builtin_amdgcn_global_load_lds( \
    (const __attribute__((address_space(1))) void*)(g), \
    (__attribute__((address_space(3))) void*)(l), 16, 0, 0)

#define STAGE(P, pf32, eoff, dst8) do {                                        \
    if (!(pf32)) { GLD16(((const u16*)(P)) + (eoff), (dst8)); }                \
    else {                                                                     \
        const float* _p = ((const float*)(P)) + (eoff);                        \
        f32x4 _a = *(const f32x4*)_p, _b = *(const f32x4*)(_p + 4);            \
        short8 _s;                                                             \
        _s[0]=(short)f2bf(_a[0]); _s[1]=(short)f2bf(_a[1]);                    \
        _s[2]=(short)f2bf(_a[2]); _s[3]=(short)f2bf(_a[3]);                    \
        _s[4]=(short)f2bf(_b[0]); _s[5]=(short)f2bf(_b[1]);                    \
        _s[6]=(short)f2bf(_b[2]); _s[7]=(short)f2bf(_b[3]);                    \
        *(short8*)(dst8) = _s;                                                 \
    } } while (0)

// ---------------------------------------------------------------------------
// Probe: flags[0]=1 -> inputs fp32; flags[1]=1 -> mask is bool bytes.
// ---------------------------------------------------------------------------
__global__ __launch_bounds__(64) void probe_kernel(
    const void* __restrict__ x, const void* __restrict__ pad,
    int* __restrict__ flags, int* __restrict__ flagsA)
{
    const int lane = threadIdx.x;
    const u16* xu = (const u16*)x;
    const unsigned int e = (xu[lane * 2] >> 7) & 0xFF;
    const int sane = (e >= 0x70 && e <= 0x8F) ? 1 : 0;
    unsigned long long m = __ballot(sane);
    const int f32 = (__popcll(m) < 32) ? 1 : 0;

    const unsigned int* pi = (const unsigned int*)pad;
    int bytes = 0;
#pragma unroll
    for (int j = 0; j < 6; j++) {
        unsigned int v = pi[128 + j * 64 + lane];
        if (v > 1u) bytes = 1;
    }
    m = __ballot(bytes);
    if (lane == 0) {
        flags[0] = f32; flags[1] = (m != 0ULL) ? 1 : 0;
        flagsA[0] = 0;  flagsA[1] = 0;
    }
}

__global__ __launch_bounds__(256) void conv4(
    const void* __restrict__ src, u16* __restrict__ dst, int n4,
    const int* __restrict__ flags)
{
    const int i = blockIdx.x * 256 + threadIdx.x;
    if (i >= n4) return;
    if (flags[0]) {
        f32x4 v = ((const f32x4*)src)[i];
        short4v s;
        s[0] = (short)f2bf(v[0]); s[1] = (short)f2bf(v[1]);
        s[2] = (short)f2bf(v[2]); s[3] = (short)f2bf(v[3]);
        ((short4v*)dst)[i] = s;
    } else {
        ((short4v*)dst)[i] = ((const short4v*)src)[i];
    }
}

__global__ __launch_bounds__(256) void mask_to_bias(
    const void* __restrict__ pad, float* __restrict__ out,
    const int* __restrict__ flags)
{
    const int i = blockIdx.x * 256 + threadIdx.x;
    const int mv = flags[1] ? (int)((const unsigned char*)pad)[i]
                            : ((const int*)pad)[i];
    out[i] = mv ? -1e30f : 0.0f;
}

// ---------------------------------------------------------------------------
// Shared GEMM core: 128x128 tile, BK=32, 256 threads (4 waves, 4x4 mfma each).
// (retained for tier C and gemm_qkv)
// ---------------------------------------------------------------------------
#define GEMM_CORE(Av, ASEL, a_row0, Wv, w_off, ldw, K)                        \
    __shared__ __align__(16) u16 As[128 * 32];                                \
    __shared__ __align__(16) u16 Bs[128 * 32];                                \
    const int inf32 = flags[0];                                               \
    const int af32  = (ASEL) ? inf32 : 0;                                     \
    const int tid  = threadIdx.x;                                             \
    const int lane = tid & 63;                                                \
    const int wave = tid >> 6;                                                \
    const int lc   = lane & 15;                                               \
    const int quad = lane >> 4;                                               \
    const int m0 = blockIdx.x * 128;                                          \
    const int n0 = blockIdx.y * 128;                                          \
    const int wm = (wave >> 1) * 64;                                          \
    const int wn = (wave & 1) * 64;                                           \
    const int r0 = tid >> 2;                                                  \
    const int ko = (tid & 3) * 8;                                             \
    f32x4 acc[4][4] = {};                                                     \
    for (int k0 = 0; k0 < (K); k0 += 32) {                                    \
        STAGE(Av, af32, ((size_t)(a_row0) + m0 + r0) * (K) + k0 + ko,         \
              &As[tid * 8]);                                                  \
        STAGE(Av, af32, ((size_t)(a_row0) + m0 + r0 + 64) * (K) + k0 + ko,    \
              &As[2048 + tid * 8]);                                           \
        STAGE(Wv, inf32, (size_t)(w_off) + (size_t)(n0 + r0) * (ldw) + k0 + ko,\
              &Bs[tid * 8]);                                                  \
        STAGE(Wv, inf32, (size_t)(w_off) + (size_t)(n0 + r0 + 64) * (ldw) + k0 + ko,\
              &Bs[2048 + tid * 8]);                                           \
        __syncthreads();                                                      \
        short8 afr[4], bfr[4];                                                \
        const int qd = quad * 8;                                              \
        _Pragma("unroll")                                                     \
        for (int mt = 0; mt < 4; mt++)                                        \
            afr[mt] = *(const short8*)&As[(wm + mt * 16 + lc) * 32 + qd];     \
        _Pragma("unroll")                                                     \
        for (int nt = 0; nt < 4; nt++)                                        \
            bfr[nt] = *(const short8*)&Bs[(wn + nt * 16 + lc) * 32 + qd];     \
        _Pragma("unroll")                                                     \
        for (int mt = 0; mt < 4; mt++)                                        \
            _Pragma("unroll")                                                 \
            for (int nt = 0; nt < 4; nt++)                                    \
                acc[mt][nt] = __builtin_amdgcn_mfma_f32_16x16x32_bf16(        \
                    afr[mt], bfr[nt], acc[mt][nt], 0, 0, 0);                  \
        __syncthreads();                                                      \
    }                                                                         \
    const int ce0 = n0 + wn + lc;                                             \
    const int re0 = m0 + wm + quad * 4;

// Generic GEMM: C = A @ W^T + bias.  EPI: 0 bias, 1 +resid, 2 +relu.
template<int EPI>
__global__ __launch_bounds__(256, 2) void gemm_bt(
    const void* __restrict__ A, int a_sel, long a_row0,
    const void* __restrict__ W, long w_off,
    const void* __restrict__ bias, long b_off,
    const void* __restrict__ resid, int r_sel, long r_row0,
    u16* __restrict__ C, long c_row0,
    int N, int K, int ldw, const int* __restrict__ flags)
{
    GEMM_CORE(A, a_sel, a_row0, W, w_off, ldw, K)
    const int rf32 = r_sel ? inf32 : 0;
#pragma unroll
    for (int mt = 0; mt < 4; mt++) {
#pragma unroll
        for (int nt = 0; nt < 4; nt++) {
            const int c = ce0 + nt * 16;
            const float bv = ldx(bias, (size_t)b_off + c, inf32);
#pragma unroll
            for (int i = 0; i < 4; i++) {
                const int r = re0 + mt * 16 + i;
                float v = acc[mt][nt][i] + bv;
                if (EPI == 1)
                    v += ldx(resid, ((size_t)r_row0 + r) * N + c, rf32);
                if (EPI == 2) v = fmaxf(v, 0.0f);
                C[((size_t)c_row0 + r) * N + c] = f2bf(v);
            }
        }
    }
}

// QKV GEMM (N=3072): Q (scaled 1/8) -> global rows of Qo (row-major);
// K -> local rows row-major; V -> local Vt[bh_local][64][1024] (transposed).
__global__ __launch_bounds__(256, 2) void gemm_qkv(
    const void* __restrict__ A, long a_row0,
    const void* __restrict__ W, const void* __restrict__ bias,
    u16* __restrict__ Qo, u16* __restrict__ Ko, u16* __restrict__ Vt,
    const int* __restrict__ flags)
{
    GEMM_CORE(A, 1, a_row0, W, 0, 1024, 1024)
    if (n0 < 1024) {
#pragma unroll
        for (int mt = 0; mt < 4; mt++)
#pragma unroll
            for (int nt = 0; nt < 4; nt++) {
                const int c = ce0 + nt * 16;
                const float bv = ldx(bias, c, inf32);
#pragma unroll
                for (int i = 0; i < 4; i++) {
                    const int r = re0 + mt * 16 + i;
                    Qo[((size_t)a_row0 + r) * 1024 + c] =
                        f2bf((acc[mt][nt][i] + bv) * 0.125f);
                }
            }
    } else if (n0 < 2048) {
#pragma unroll
        for (int mt = 0; mt < 4; mt++)
#pragma unroll
            for (int nt = 0; nt < 4; nt++) {
                const int c = ce0 + nt * 16;
                const float bv = ldx(bias, c, inf32);
#pragma unroll
                for (int i = 0; i < 4; i++) {
                    const int r = re0 + mt * 16 + i;
                    Ko[(size_t)r * 1024 + (c - 1024)] = f2bf(acc[mt][nt][i] + bv);
                }
            }
    } else {
#pragma unroll
        for (int mt = 0; mt < 4; mt++)
#pragma unroll
            for (int nt = 0; nt < 4; nt++) {
                const int c = ce0 + nt * 16;
                const float bv = ldx(bias, c, inf32);
                const int cv = c - 2048;
                const int hh = cv >> 6, d = cv & 63;
                const int rb = re0 + mt * 16;
                const int bl = rb >> 10, t = rb & 1023;
                short4v pk;
#pragma unroll
                for (int i = 0; i < 4; i++)
                    pk[i] = (short)f2bf(acc[mt][nt][i] + bv);
                *(short4v*)&Vt[((size_t)(bl * 16 + hh) * 64 + d) * 1024 + t] = pk;
            }
    }
}

// fc2 K-chunk accumulating into fp32 (tier C only)
__global__ __launch_bounds__(256, 2) void gemm_accf32(
    const void* __restrict__ A, const void* __restrict__ W, long w_off,
    const void* __restrict__ bias, const u16* __restrict__ resid, long r_row0,
    float* __restrict__ C, int ldw, int init, const int* __restrict__ flags)
{
    GEMM_CORE(A, 0, 0, W, w_off, ldw, 1024)
#pragma unroll
    for (int mt = 0; mt < 4; mt++) {
#pragma unroll
        for (int nt = 0; nt < 4; nt++) {
            const int c = ce0 + nt * 16;
            const float bv = ldx(bias, c, inf32);
#pragma unroll
            for (int i = 0; i < 4; i++) {
                const int r = re0 + mt * 16 + i;
                float v = acc[mt][nt][i];
                if (init) v += bv + bf2f(resid[((size_t)r_row0 + r) * 1024 + c]);
                else      v += C[(size_t)r * 1024 + c];
                C[(size_t)r * 1024 + c] = v;
            }
        }
    }
}

// ---------------------------------------------------------------------------
// 8-phase 256x256 GEMM (HK-style schedule, plain HIP). bf16 only.
//   C = A @ W^T + bias  (+resid EPI=1, relu EPI=2)
// 512 threads = 8 waves (2M x 4N), per-wave 128x64 output, BK=64.
// LDS: 2 tile-buffers x 2 K-halves x [256 rows][32 cols] for A and B = 128 KiB.
// Per K-tile: 4 phases {ds_read frags || stage 1 half-tile -> barrier ->
// lgkmcnt(0) -> setprio(1) -> 16 MFMA -> setprio(0) -> barrier}; counted
// vmcnt(4) once per K-tile (prefetch of tile t+2 kc0 stays in flight).
// Staging order: p1 (t+1).Akc1, p2 (t+1).Bkc1, p3 (t+2).Akc0, p4 (t+2).Bkc0
// -- every LDS half is overwritten >=1 end-barrier after its last ds_read.
// Swizzle: 16B chunk index ^= row>>1 (bits 4-5 of byte addr), applied on the
// pre-swizzled global source (linear LDS dest, rule "both-sides-or-neither")
// and on the ds_read address -> 2-way (free) bank pattern on frag reads.
// ---------------------------------------------------------------------------
template<int EPI>
__global__ __launch_bounds__(512, 2) void gemm8(
    const u16* __restrict__ A, const u16* __restrict__ W,
    const u16* __restrict__ bias, const u16* __restrict__ resid,
    u16* __restrict__ C, int N, int K)
{
    __shared__ __align__(16) u16 As8[2][2][8192];
    __shared__ __align__(16) u16 Bs8[2][2][8192];
    const int tid  = threadIdx.x;
    const int lane = tid & 63;
    const int lc   = lane & 15;
    const int quad = lane >> 4;
    const int w    = tid >> 6;
    const int wr   = w >> 2;     // 0..1 : M half
    const int wc   = w & 3;      // 0..3 : N quarter
    const int m0 = blockIdx.x * 256;
    const int n0 = blockIdx.y * 256;

    // staging map: thread covers LDS 16B groups g = tid and 512+tid of a half;
    // row = g>>2, chunk = g&3; global col chunk = chunk ^ (row>>1 & 3).
    const int sr   = tid >> 2;                                   // 0..127
    const int scol = ((((tid & 3) << 4) ^ (((tid >> 3) & 3) << 4)) >> 1);
    const size_t aoff0 = (size_t)(m0 + sr) * K + scol;
    const size_t aoff1 = (size_t)(m0 + 128 + sr) * K + scol;
    const size_t boff0 = (size_t)(n0 + sr) * K + scol;
    const size_t boff1 = (size_t)(n0 + 128 + sr) * K + scol;

    // frag-read swizzled 16B-chunk offset (elements): (quad ^ (lc>>1)&3) * 8
    const int fsw   = (quad ^ ((lc >> 1) & 3)) << 3;
    const int aBase = (wr * 128 + lc) * 32 + fsw;
    const int bBase = (wc * 64 + lc) * 32 + fsw;

#define SA8(buf, kc, tb) do { \
    GLD16(A + aoff0 + (tb) + (kc) * 32, &As8[buf][kc][tid * 8]); \
    GLD16(A + aoff1 + (tb) + (kc) * 32, &As8[buf][kc][4096 + tid * 8]); } while (0)
#define SB8(buf, kc, tb) do { \
    GLD16(W + boff0 + (tb) + (kc) * 32, &Bs8[buf][kc][tid * 8]); \
    GLD16(W + boff1 + (tb) + (kc) * 32, &Bs8[buf][kc][4096 + tid * 8]); } while (0)
#define LDA4(KC, MH) do { _Pragma("unroll") \
    for (int q_ = 0; q_ < 4; q_++) \
        af[q_] = *(const short8*)&As8[c][KC][aBase + ((MH) * 4 + q_) * 512]; } while (0)
#define LDB4(KC) do { _Pragma("unroll") \
    for (int q_ = 0; q_ < 4; q_++) \
        bf[q_] = *(const short8*)&Bs8[c][KC][bBase + q_ * 512]; } while (0)
#define MFMA16(MH) do { _Pragma("unroll") \
    for (int mq = 0; mq < 4; mq++) { _Pragma("unroll") \
    for (int nq = 0; nq < 4; nq++) \
        acc[(MH) * 4 + mq][nq] = __builtin_amdgcn_mfma_f32_16x16x32_bf16( \
            af[mq], bf[nq], acc[(MH) * 4 + mq][nq], 0, 0, 0); } } while (0)
#define BARW do { __builtin_amdgcn_s_barrier(); \
    asm volatile("s_waitcnt lgkmcnt(0)" ::: "memory"); \
    __builtin_amdgcn_s_setprio(1); } while (0)
#define BARE do { __builtin_amdgcn_s_setprio(0); \
    __builtin_amdgcn_s_barrier(); } while (0)

    f32x4 acc[8][4] = {};
    short8 af[4], bf[4];
    const int NT = K >> 6;

    // prologue: tile0 all 4 halves + tile1 kc0 halves (steady-state carry-in)
    SA8(0, 0, 0); SB8(0, 0, 0); SA8(0, 1, 0); SB8(0, 1, 0);
    if (NT > 1) { SA8(1, 0, 64); SB8(1, 0, 64); }
    if (NT > 1) asm volatile("s_waitcnt vmcnt(4)" ::: "memory");
    else        asm volatile("s_waitcnt vmcnt(0)" ::: "memory");
    __builtin_amdgcn_s_barrier();

    for (int t = 0; t < NT; ++t) {
        const int c = t & 1, nx = c ^ 1;
        const int k0 = t << 6;
        const bool s1 = (t + 1 < NT), s2 = (t + 2 < NT);
        // phase 1: kc0 x mh0
        LDA4(0, 0); LDB4(0);
        if (s1) SA8(nx, 1, k0 + 64);
        BARW; MFMA16(0); BARE;
        // phase 2: kc0 x mh1 (B kc0 frags reused)
        LDA4(0, 1);
        if (s1) SB8(nx, 1, k0 + 64);
        BARW; MFMA16(1); BARE;
        // phase 3: kc1 x mh0
        LDA4(1, 0); LDB4(1);
        if (s2) SA8(c, 0, k0 + 128);
        BARW; MFMA16(0); BARE;
        // phase 4: kc1 x mh1, counted vmcnt before tile swap
        LDA4(1, 1);
        if (s2) SB8(c, 0, k0 + 128);
        BARW; MFMA16(1);
        __builtin_amdgcn_s_setprio(0);
        if (s2) asm volatile("s_waitcnt vmcnt(4)" ::: "memory");
        else    asm volatile("s_waitcnt vmcnt(0)" ::: "memory");
        __builtin_amdgcn_s_barrier();
    }

    // epilogue: C row = m0 + wr*128 + mt*16 + quad*4 + i, col = n0 + wc*64 + nt*16 + lc
    const int cb0 = n0 + wc * 64 + lc;
    const int rb0 = m0 + wr * 128 + quad * 4;
#pragma unroll
    for (int mt = 0; mt < 8; mt++) {
#pragma unroll
        for (int nt = 0; nt < 4; nt++) {
            const int cN = cb0 + nt * 16;
            const float bv = bf2f(bias[cN]);
#pragma unroll
            for (int i = 0; i < 4; i++) {
                const int rM = rb0 + mt * 16 + i;
                float v = acc[mt][nt][i] + bv;
                if (EPI == 1) v += bf2f(resid[(size_t)rM * N + cN]);
                if (EPI == 2) v = fmaxf(v, 0.0f);
                C[(size_t)rM * N + cN] = f2bf(v);
            }
        }
    }
#undef SA8
#undef SB8
#undef LDA4
#undef LDB4
#undef MFMA16
#undef BARW
#undef BARE
}

// ---------------------------------------------------------------------------
// Flash attention v3: paired q-tiles (qt, 7-qt) of 128 rows -> uniform 18
// k-tile units/block. Double-buffered K/V staging (prefetch kt+1 before the
// compute of kt; the compiler's vmcnt drain at the single loop barrier lands
// after ~1000 cyc of softmax+MFMA). Mask-bias column preloaded to LDS.
// Grid (4, nbh). In-place Q->O in QO.
// ---------------------------------------------------------------------------
__global__ __launch_bounds__(256, 2) void attn_kernel(
    u16* __restrict__ QO, const u16* __restrict__ Ko,
    const u16* __restrict__ Vt, const float* __restrict__ kb, int b0)
{
    __shared__ __align__(16) u16 Qs[2 * 128 * 32];   // [kcd][qrow][32]
    __shared__ __align__(16) u16 Ks[2][2 * 64 * 32]; // dbuf [kcd][key][32]
    __shared__ __align__(16) u16 Vs[2][2 * 64 * 32]; // dbuf [kck][d][32]
    __shared__ __align__(16) u16 Ps[4][32 * 72];
    __shared__ float kba[1024];

    const int tid  = threadIdx.x;
    const int lane = tid & 63;
    const int w    = tid >> 6;
    const int lc   = lane & 15;
    const int quad = lane >> 4;
    const int bl = blockIdx.y >> 4;
    const int h  = blockIdx.y & 15;
    const int b  = b0 + bl;

    // preload padding-bias column for this sequence
    *(f32x4*)&kba[tid * 4] = *(const f32x4*)&kb[b * 1024 + tid * 4];

    for (int p = 0; p < 2; p++) {
        const int qt = p ? 7 - (int)blockIdx.x : (int)blockIdx.x;

        // stage Q tile [kcd][128][32]
#pragma unroll
        for (int it = 0; it < 4; it++) {
            const int kcd = it >> 1, half = it & 1;
            const int r = half * 64 + (tid >> 2);
            const int c = kcd * 32 + (tid & 3) * 8;
            GLD16(&QO[((size_t)(b * 1024 + qt * 128 + r)) * 1024 + h * 64 + c],
                  &Qs[kcd * 4096 + half * 2048 + tid * 8]);
        }
        // stage kt=0 into buffer 0
        {
            const int rr = tid >> 2;
#pragma unroll
            for (int it = 0; it < 2; it++) {
                const int cc = it * 32 + (tid & 3) * 8;
                GLD16(&Ko[((size_t)(bl * 1024 + rr)) * 1024 + h * 64 + cc],
                      &Ks[0][it * 2048 + tid * 8]);
                GLD16(&Vt[((size_t)(bl * 16 + h) * 64 + rr) * 1024 + cc],
                      &Vs[0][it * 2048 + tid * 8]);
            }
        }
        __syncthreads();   // Q + K0/V0 (+ kba on p=0) ready

        short8 aq[2][2];
#pragma unroll
        for (int mt = 0; mt < 2; mt++)
#pragma unroll
            for (int kc = 0; kc < 2; kc++)
                aq[mt][kc] = *(const short8*)
                    &Qs[kc * 4096 + (w * 32 + mt * 16 + lc) * 32 + quad * 8];

        f32x4 o[2][4] = {};
        float m_i[2][4], l_i[2][4];
#pragma unroll
        for (int mt = 0; mt < 2; mt++)
#pragma unroll
            for (int i = 0; i < 4; i++) { m_i[mt][i] = -1e30f; l_i[mt][i] = 0.0f; }

        const int ktmax = 2 * qt + 2;
        for (int kt = 0; kt < ktmax; kt++) {
            const int cur = kt & 1;
            // prefetch kt+1 (overlaps with compute below; drained at barrier)
            if (kt + 1 < ktmax) {
                const int nxt = cur ^ 1;
                const int rr = tid >> 2;
#pragma unroll
                for (int it = 0; it < 2; it++) {
                    const int cc = it * 32 + (tid & 3) * 8;
                    GLD16(&Ko[((size_t)(bl * 1024 + (kt + 1) * 64 + rr)) * 1024 + h * 64 + cc],
                          &Ks[nxt][it * 2048 + tid * 8]);
                    GLD16(&Vt[((size_t)(bl * 16 + h) * 64 + rr) * 1024 + (kt + 1) * 64 + cc],
                          &Vs[nxt][it * 2048 + tid * 8]);
                }
            }

            // S = Q K^T
            short8 bk[4][2];
#pragma unroll
            for (int nt = 0; nt < 4; nt++)
#pragma unroll
                for (int kc = 0; kc < 2; kc++)
                    bk[nt][kc] = *(const short8*)
                        &Ks[cur][kc * 2048 + (nt * 16 + lc) * 32 + quad * 8];

            f32x4 s[2][4];
#pragma unroll
            for (int mt = 0; mt < 2; mt++)
#pragma unroll
                for (int nt = 0; nt < 4; nt++) {
                    f32x4 z = {};
#pragma unroll
                    for (int kc = 0; kc < 2; kc++)
                        z = __builtin_amdgcn_mfma_f32_16x16x32_bf16(
                            aq[mt][kc], bk[nt][kc], z, 0, 0, 0);
                    s[mt][nt] = z;
                }

            const int causal = (kt >= 2 * qt);   // block-uniform
            float al[2][4];
#pragma unroll
            for (int mt = 0; mt < 2; mt++) {
                const int qg0 = qt * 128 + w * 32 + mt * 16 + quad * 4;
#pragma unroll
                for (int nt = 0; nt < 4; nt++) {
                    const int kg = kt * 64 + nt * 16 + lc;
                    const float kbv = kba[kt * 64 + nt * 16 + lc];
#pragma unroll
                    for (int i = 0; i < 4; i++) {
                        float sv = s[mt][nt][i] + kbv;
                        if (causal && kg > qg0 + i) sv = -1e30f;
                        s[mt][nt][i] = sv;
                    }
                }
                float mnew[4], rs[4];
#pragma unroll
                for (int i = 0; i < 4; i++) {
                    float rm = fmaxf(fmaxf(s[mt][0][i], s[mt][1][i]),
                                     fmaxf(s[mt][2][i], s[mt][3][i]));
                    rm = fmaxf(rm, __shfl_xor(rm, 1));
                    rm = fmaxf(rm, __shfl_xor(rm, 2));
                    rm = fmaxf(rm, __shfl_xor(rm, 4));
                    rm = fmaxf(rm, __shfl_xor(rm, 8));
                    mnew[i] = fmaxf(m_i[mt][i], rm);
                    al[mt][i] = exp2f((m_i[mt][i] - mnew[i]) * 1.442695041f);
                    rs[i] = 0.0f;
                }
#pragma unroll
                for (int nt = 0; nt < 4; nt++)
#pragma unroll
                    for (int i = 0; i < 4; i++) {
                        float pp = exp2f((s[mt][nt][i] - mnew[i]) * 1.442695041f);
                        s[mt][nt][i] = pp;
                        rs[i] += pp;
                    }
#pragma unroll
                for (int i = 0; i < 4; i++) {
                    float r = rs[i];
                    r += __shfl_xor(r, 1);
                    r += __shfl_xor(r, 2);
                    r += __shfl_xor(r, 4);
                    r += __shfl_xor(r, 8);
                    l_i[mt][i] = l_i[mt][i] * al[mt][i] + r;
                    m_i[mt][i] = mnew[i];
                }
#pragma unroll
                for (int nt = 0; nt < 4; nt++)
#pragma unroll
                    for (int i = 0; i < 4; i++)
                        Ps[w][(mt * 16 + quad * 4 + i) * 72 + nt * 16 + lc] =
                            f2bf(s[mt][nt][i]);
            }

            // O = O*alpha + P @ V
            short8 ap[2][2], bv2[4][2];
#pragma unroll
            for (int mt = 0; mt < 2; mt++)
#pragma unroll
                for (int kc = 0; kc < 2; kc++)
                    ap[mt][kc] = *(const short8*)
                        &Ps[w][(mt * 16 + lc) * 72 + kc * 32 + quad * 8];
#pragma unroll
            for (int nt = 0; nt < 4; nt++)
#pragma unroll
                for (int kc = 0; kc < 2; kc++)
                    bv2[nt][kc] = *(const short8*)
                        &Vs[cur][kc * 2048 + (nt * 16 + lc) * 32 + quad * 8];
#pragma unroll
            for (int mt = 0; mt < 2; mt++)
#pragma unroll
                for (int nt = 0; nt < 4; nt++) {
                    f32x4 oo = o[mt][nt];
#pragma unroll
                    for (int i = 0; i < 4; i++) oo[i] *= al[mt][i];
#pragma unroll
                    for (int kc = 0; kc < 2; kc++)
                        oo = __builtin_amdgcn_mfma_f32_16x16x32_bf16(
                            ap[mt][kc], bv2[nt][kc], oo, 0, 0, 0);
                    o[mt][nt] = oo;
                }
            __syncthreads();   // prefetch drained; buffers safe to swap
        }

        // write O in place of Q (exclusive slice)
#pragma unroll
        for (int mt = 0; mt < 2; mt++)
#pragma unroll
            for (int i = 0; i < 4; i++) {
                const float inv = l_i[mt][i] > 0.0f ? 1.0f / l_i[mt][i] : 0.0f;
#pragma unroll
                for (int nt = 0; nt < 4; nt++) {
                    const int r = qt * 128 + w * 32 + mt * 16 + quad * 4 + i;
                    const int d = nt * 16 + lc;
                    QO[((size_t)(b * 1024 + r)) * 1024 + h * 64 + d] =
                        f2bf(o[mt][nt][i] * inv);
                }
            }
    }
}

// ---------------------------------------------------------------------------
// LayerNorm, one block/row, biased variance, eps=1e-12.
// ---------------------------------------------------------------------------
template<int IN16, int OUTSEL>
__global__ __launch_bounds__(256) void ln_kernel(
    const void* __restrict__ yv, const void* __restrict__ w,
    const void* __restrict__ bb, void* __restrict__ o, long o_row0,
    const int* __restrict__ flags)
{
    const int row = blockIdx.x;
    const int tid = threadIdx.x;
    const int inf32 = flags[0];
    float x0, x1, x2, x3;
    if (IN16) {
        const u16* p = (const u16*)yv + (size_t)row * 1024 + tid * 4;
        short4v v = *(const short4v*)p;
        x0 = bf2f((u16)v[0]); x1 = bf2f((u16)v[1]);
        x2 = bf2f((u16)v[2]); x3 = bf2f((u16)v[3]);
    } else {
        const float* p = (const float*)yv + (size_t)row * 1024 + tid * 4;
        f32x4 v = *(const f32x4*)p;
        x0 = v[0]; x1 = v[1]; x2 = v[2]; x3 = v[3];
    }
    float s = x0 + x1 + x2 + x3;
    float q = x0 * x0 + x1 * x1 + x2 * x2 + x3 * x3;
#pragma unroll
    for (int off = 32; off; off >>= 1) {
        s += __shfl_xor(s, off);
        q += __shfl_xor(q, off);
    }
    __shared__ float sm[8];
    const int lane = tid & 63, wv = tid >> 6;
    if (lane == 0) { sm[wv] = s; sm[4 + wv] = q; }
    __syncthreads();
    const float ts = sm[0] + sm[1] + sm[2] + sm[3];
    const float tq = sm[4] + sm[5] + sm[6] + sm[7];
    const float mean = ts * (1.0f / 1024.0f);
    float var = tq * (1.0f / 1024.0f) - mean * mean;
    if (var < 0.0f) var = 0.0f;
    const float rinv = rsqrtf(var + 1e-12f);

    const size_t obase = ((size_t)o_row0 + row) * 1024 + tid * 4;
#pragma unroll
    for (int j = 0; j < 4; j++) {
        const int c = tid * 4 + j;
        float xv = (j == 0) ? x0 : (j == 1) ? x1 : (j == 2) ? x2 : x3;
        float v = ldx(w, c, inf32) * ((xv - mean) * rinv) + ldx(bb, c, inf32);
        if (OUTSEL && inf32) ((float*)o)[obase + j] = v;
        else                 ((u16*)o)[obase + j] = f2bf(v);
    }
}

// ---------------------------------------------------------------------------
extern "C" void kernel_launch(void* const* d_in, const int* in_sizes, int n_in,
                              void* d_out, int out_size, void* d_ws, size_t ws_size,
                              hipStream_t stream)
{
    const void* x     = d_in[0];
    const void* in_w  = d_in[1];
    const void* in_b  = d_in[2];
    const void* out_w = d_in[3];
    const void* out_b = d_in[4];
    const void* fc1_w = d_in[5];
    const void* fc1_b = d_in[6];
    const void* fc2_w = d_in[7];
    const void* fc2_b = d_in[8];
    const void* ln1w  = d_in[9];
    const void* ln1b  = d_in[10];
    const void* ln2w  = d_in[11];
    const void* ln2b  = d_in[12];
    const void* pad   = d_in[13];
    u16* outp = (u16*)d_out;
    char* ws = (char*)d_ws;
    dim3 blk(256);
    dim3 blk8(512);

    const size_t MB = 1024 * 1024;
    const bool bigWS = ws_size >= (105 * MB + 64 * 1024);

    if (bigWS) {
        // Tier A layout:
        //  0-16  xb -> x1        16-22 w1b (dead after qkv) \
        //  22-24 wob (dead after proj)  24-32 f1b (dead after fc1) } -> y2 16-32
        //  32-40 f2b   40-41 biases     41-57 Ko    57-73 Vt
        //  73-89 y1    41-105 h (FF)    105+ flags / kbias
        u16*   xb   = (u16*)(ws + 0);
        u16*   x1   = (u16*)(ws + 0);
        u16*   w1b  = (u16*)(ws + 16 * MB);
        u16*   wob  = (u16*)(ws + 22 * MB);
        u16*   f1b  = (u16*)(ws + 24 * MB);
        u16*   f2b  = (u16*)(ws + 32 * MB);
        u16*   inbb = (u16*)(ws + 40 * MB);
        u16*   outbb= (u16*)(ws + 40 * MB + 8192);
        u16*   f1bb = (u16*)(ws + 40 * MB + 16384);
        u16*   f2bb = (u16*)(ws + 40 * MB + 24576);
        u16*   Ko   = (u16*)(ws + 41 * MB);
        u16*   Vt   = (u16*)(ws + 57 * MB);
        u16*   y1   = (u16*)(ws + 73 * MB);
        u16*   h    = (u16*)(ws + 41 * MB);
        u16*   y2   = (u16*)(ws + 16 * MB);
        int*   flags  = (int*)(ws + 105 * MB);
        int*   flagsA = (int*)(ws + 105 * MB + 32);
        float* kbias  = (float*)(ws + 105 * MB + 64);

        probe_kernel<<<dim3(1), dim3(64), 0, stream>>>(x, pad, flags, flagsA);
        mask_to_bias<<<dim3(32), blk, 0, stream>>>(pad, kbias, flags);
        conv4<<<dim3(8192), blk, 0, stream>>>(x, xb, 2097152, flags);
        conv4<<<dim3(3072), blk, 0, stream>>>(in_w, w1b, 786432, flags);
        conv4<<<dim3(1024), blk, 0, stream>>>(out_w, wob, 262144, flags);
        conv4<<<dim3(4096), blk, 0, stream>>>(fc1_w, f1b, 1048576, flags);
        conv4<<<dim3(4096), blk, 0, stream>>>(fc2_w, f2b, 1048576, flags);
        conv4<<<dim3(3), blk, 0, stream>>>(in_b, inbb, 768, flags);
        conv4<<<dim3(1), blk, 0, stream>>>(out_b, outbb, 256, flags);
        conv4<<<dim3(4), blk, 0, stream>>>(fc1_b, f1bb, 1024, flags);
        conv4<<<dim3(1), blk, 0, stream>>>(fc2_b, f2bb, 256, flags);

        gemm_qkv<<<dim3(64, 24), blk, 0, stream>>>(
            xb, 0, w1b, inbb, outp, Ko, Vt, flagsA);
        attn_kernel<<<dim3(4, 128), blk, 0, stream>>>(outp, Ko, Vt, kbias, 0);
        // out-proj: y1 = attn @ wob^T + outbb + xb   [8192,1024] K=1024
        gemm8<1><<<dim3(32, 4), blk8, 0, stream>>>(
            outp, wob, outbb, xb, y1, 1024, 1024);
        ln_kernel<1, 0><<<dim3(8192), blk, 0, stream>>>(y1, ln1w, ln1b, x1, 0, flags);
        // fc1: h = relu(x1 @ f1b^T + f1bb)   [8192,4096] K=1024
        gemm8<2><<<dim3(32, 16), blk8, 0, stream>>>(
            x1, f1b, f1bb, nullptr, h, 4096, 1024);
        // fc2: y2 = h @ f2b^T + f2bb + x1    [8192,1024] K=4096
        gemm8<1><<<dim3(32, 4), blk8, 0, stream>>>(
            h, f2b, f2bb, x1, y2, 1024, 4096);
        ln_kernel<1, 1><<<dim3(8192), blk, 0, stream>>>(y2, ln2w, ln2b, d_out, 0, flags);
    } else {
        // Tier C: quartered, 12.6 MB workspace
        u16*   Ko    = (u16*)(ws + 0);
        u16*   Vt    = (u16*)(ws + 4 * MB);
        u16*   y1h   = (u16*)(ws + 0);
        float* acc   = (float*)(ws + 0);
        u16*   hc    = (u16*)(ws + 8 * MB);
        int*   flags  = (int*)(ws + 12 * MB);
        int*   flagsA = (int*)(ws + 12 * MB + 32);
        float* kbias  = (float*)(ws + 12 * MB + 64);

        probe_kernel<<<dim3(1), dim3(64), 0, stream>>>(x, pad, flags, flagsA);
        mask_to_bias<<<dim3(32), blk, 0, stream>>>(pad, kbias, flags);

        for (int q = 0; q < 4; q++) {
            const long r0 = (long)q * 2048;
            gemm_qkv<<<dim3(16, 24), blk, 0, stream>>>(
                x, r0, in_w, in_b, outp, Ko, Vt, flags);
            attn_kernel<<<dim3(4, 32), blk, 0, stream>>>(
                outp, Ko, Vt, kbias, q * 2);
        }
        for (int hf = 0; hf < 2; hf++) {
            const long r0 = (long)hf * 4096;
            gemm_bt<1><<<dim3(32, 8), blk, 0, stream>>>(
                outp, 0, r0, out_w, 0, out_b, 0, x, 1, r0,
                y1h, 0, 1024, 1024, 1024, flags);
            ln_kernel<1, 0><<<dim3(4096), blk, 0, stream>>>(
                y1h, ln1w, ln1b, outp, r0, flags);
        }
        for (int q = 3; q >= 0; q--) {
            const long r0 = (long)q * 2048;
            for (int c = 0; c < 4; c++) {
                gemm_bt<2><<<dim3(16, 8), blk, 0, stream>>>(
                    outp, 0, r0, fc1_w, (long)c * 1024 * 1024, fc1_b, (long)c * 1024,
                    nullptr, 0, 0, hc, 0, 1024, 1024, 1024, flags);
                gemm_accf32<<<dim3(16, 8), blk, 0, stream>>>(
                    hc, fc2_w, (long)c * 1024, fc2_b, outp, r0,
                    acc, 4096, c == 0, flags);
            }
            ln_kernel<0, 1><<<dim3(2048), blk, 0, stream>>>(
                acc, ln2w, ln2b, d_out, r0, flags);
        }
    }
}

// Round 2
// 531.677 us; speedup vs baseline: 1.1496x; 1.0910x over previous
//
#include <hip/hip_runtime.h>

typedef unsigned short u16;
typedef __attribute__((ext_vector_type(8))) short short8;
typedef __attribute__((ext_vector_type(4))) short short4v;
typedef __attribute__((ext_vector_type(4))) float f32x4;

#define DEV static __device__ __forceinline__

DEV float bf2f(u16 h) {
    union { unsigned int u; float f; } v; v.u = ((unsigned int)h) << 16; return v.f;
}
DEV u16 f2bf(float f) {
    union { float f; unsigned int u; } v; v.f = f;
    unsigned int r = (v.u + 0x7fff + ((v.u >> 16) & 1)) >> 16;
    return (u16)r;
}
DEV float ldx(const void* p, size_t i, int f32) {
    return f32 ? ((const float*)p)[i] : bf2f(((const u16*)p)[i]);
}

#define GLD16(g, l) __builtin_amdgcn_global_load_lds( \
    (const __attribute__((address_space(1))) void*)(g), \
    (__attribute__((address_space(3))) void*)(l), 16, 0, 0)

#define STAGE(P, pf32, eoff, dst8) do {                                        \
    if (!(pf32)) { GLD16(((const u16*)(P)) + (eoff), (dst8)); }                \
    else {                                                                     \
        const float* _p = ((const float*)(P)) + (eoff);                        \
        f32x4 _a = *(const f32x4*)_p, _b = *(const f32x4*)(_p + 4);            \
        short8 _s;                                                             \
        _s[0]=(short)f2bf(_a[0]); _s[1]=(short)f2bf(_a[1]);                    \
        _s[2]=(short)f2bf(_a[2]); _s[3]=(short)f2bf(_a[3]);                    \
        _s[4]=(short)f2bf(_b[0]); _s[5]=(short)f2bf(_b[1]);                    \
        _s[6]=(short)f2bf(_b[2]); _s[7]=(short)f2bf(_b[3]);                    \
        *(short8*)(dst8) = _s;                                                 \
    } } while (0)

// ---------------------------------------------------------------------------
// Probe: flags[0]=1 -> inputs fp32; flags[1]=1 -> mask is bool bytes.
// ---------------------------------------------------------------------------
__global__ __launch_bounds__(64) void probe_kernel(
    const void* __restrict__ x, const void* __restrict__ pad,
    int* __restrict__ flags, int* __restrict__ flagsA)
{
    const int lane = threadIdx.x;
    const u16* xu = (const u16*)x;
    const unsigned int e = (xu[lane * 2] >> 7) & 0xFF;
    const int sane = (e >= 0x70 && e <= 0x8F) ? 1 : 0;
    unsigned long long m = __ballot(sane);
    const int f32 = (__popcll(m) < 32) ? 1 : 0;

    const unsigned int* pi = (const unsigned int*)pad;
    int bytes = 0;
#pragma unroll
    for (int j = 0; j < 6; j++) {
        unsigned int v = pi[128 + j * 64 + lane];
        if (v > 1u) bytes = 1;
    }
    m = __ballot(bytes);
    if (lane == 0) {
        flags[0] = f32; flags[1] = (m != 0ULL) ? 1 : 0;
        flagsA[0] = 0;  flagsA[1] = 0;
    }
}

__global__ __launch_bounds__(256) void conv4(
    const void* __restrict__ src, u16* __restrict__ dst, int n4,
    const int* __restrict__ flags)
{
    const int i = blockIdx.x * 256 + threadIdx.x;
    if (i >= n4) return;
    if (flags[0]) {
        f32x4 v = ((const f32x4*)src)[i];
        short4v s;
        s[0] = (short)f2bf(v[0]); s[1] = (short)f2bf(v[1]);
        s[2] = (short)f2bf(v[2]); s[3] = (short)f2bf(v[3]);
        ((short4v*)dst)[i] = s;
    } else {
        ((short4v*)dst)[i] = ((const short4v*)src)[i];
    }
}

__global__ __launch_bounds__(256) void mask_to_bias(
    const void* __restrict__ pad, float* __restrict__ out,
    const int* __restrict__ flags)
{
    const int i = blockIdx.x * 256 + threadIdx.x;
    const int mv = flags[1] ? (int)((const unsigned char*)pad)[i]
                            : ((const int*)pad)[i];
    out[i] = mv ? -1e30f : 0.0f;
}

// ---------------------------------------------------------------------------
// Shared GEMM core: 128x128 tile, BK=32, 256 threads (4 waves, 4x4 mfma each).
// (retained for tier C)
// ---------------------------------------------------------------------------
#define GEMM_CORE(Av, ASEL, a_row0, Wv, w_off, ldw, K)                        \
    __shared__ __align__(16) u16 As[128 * 32];                                \
    __shared__ __align__(16) u16 Bs[128 * 32];                                \
    const int inf32 = flags[0];                                               \
    const int af32  = (ASEL) ? inf32 : 0;                                     \
    const int tid  = threadIdx.x;                                             \
    const int lane = tid & 63;                                                \
    const int wave = tid >> 6;                                                \
    const int lc   = lane & 15;                                               \
    const int quad = lane >> 4;                                               \
    const int m0 = blockIdx.x * 128;                                          \
    const int n0 = blockIdx.y * 128;                                          \
    const int wm = (wave >> 1) * 64;                                          \
    const int wn = (wave & 1) * 64;                                           \
    const int r0 = tid >> 2;                                                  \
    const int ko = (tid & 3) * 8;                                             \
    f32x4 acc[4][4] = {};                                                     \
    for (int k0 = 0; k0 < (K); k0 += 32) {                                    \
        STAGE(Av, af32, ((size_t)(a_row0) + m0 + r0) * (K) + k0 + ko,         \
              &As[tid * 8]);                                                  \
        STAGE(Av, af32, ((size_t)(a_row0) + m0 + r0 + 64) * (K) + k0 + ko,    \
              &As[2048 + tid * 8]);                                           \
        STAGE(Wv, inf32, (size_t)(w_off) + (size_t)(n0 + r0) * (ldw) + k0 + ko,\
              &Bs[tid * 8]);                                                  \
        STAGE(Wv, inf32, (size_t)(w_off) + (size_t)(n0 + r0 + 64) * (ldw) + k0 + ko,\
              &Bs[2048 + tid * 8]);                                           \
        __syncthreads();                                                      \
        short8 afr[4], bfr[4];                                                \
        const int qd = quad * 8;                                              \
        _Pragma("unroll")                                                     \
        for (int mt = 0; mt < 4; mt++)                                        \
            afr[mt] = *(const short8*)&As[(wm + mt * 16 + lc) * 32 + qd];     \
        _Pragma("unroll")                                                     \
        for (int nt = 0; nt < 4; nt++)                                        \
            bfr[nt] = *(const short8*)&Bs[(wn + nt * 16 + lc) * 32 + qd];     \
        _Pragma("unroll")                                                     \
        for (int mt = 0; mt < 4; mt++)                                        \
            _Pragma("unroll")                                                 \
            for (int nt = 0; nt < 4; nt++)                                    \
                acc[mt][nt] = __builtin_amdgcn_mfma_f32_16x16x32_bf16(        \
                    afr[mt], bfr[nt], acc[mt][nt], 0, 0, 0);                  \
        __syncthreads();                                                      \
    }                                                                         \
    const int ce0 = n0 + wn + lc;                                             \
    const int re0 = m0 + wm + quad * 4;

// Generic GEMM: C = A @ W^T + bias.  EPI: 0 bias, 1 +resid, 2 +relu.
template<int EPI>
__global__ __launch_bounds__(256, 2) void gemm_bt(
    const void* __restrict__ A, int a_sel, long a_row0,
    const void* __restrict__ W, long w_off,
    const void* __restrict__ bias, long b_off,
    const void* __restrict__ resid, int r_sel, long r_row0,
    u16* __restrict__ C, long c_row0,
    int N, int K, int ldw, const int* __restrict__ flags)
{
    GEMM_CORE(A, a_sel, a_row0, W, w_off, ldw, K)
    const int rf32 = r_sel ? inf32 : 0;
#pragma unroll
    for (int mt = 0; mt < 4; mt++) {
#pragma unroll
        for (int nt = 0; nt < 4; nt++) {
            const int c = ce0 + nt * 16;
            const float bv = ldx(bias, (size_t)b_off + c, inf32);
#pragma unroll
            for (int i = 0; i < 4; i++) {
                const int r = re0 + mt * 16 + i;
                float v = acc[mt][nt][i] + bv;
                if (EPI == 1)
                    v += ldx(resid, ((size_t)r_row0 + r) * N + c, rf32);
                if (EPI == 2) v = fmaxf(v, 0.0f);
                C[((size_t)c_row0 + r) * N + c] = f2bf(v);
            }
        }
    }
}

// QKV GEMM (tier C): N=3072 split epilogue on the 128x128 core.
__global__ __launch_bounds__(256, 2) void gemm_qkv(
    const void* __restrict__ A, long a_row0,
    const void* __restrict__ W, const void* __restrict__ bias,
    u16* __restrict__ Qo, u16* __restrict__ Ko, u16* __restrict__ Vt,
    const int* __restrict__ flags)
{
    GEMM_CORE(A, 1, a_row0, W, 0, 1024, 1024)
    if (n0 < 1024) {
#pragma unroll
        for (int mt = 0; mt < 4; mt++)
#pragma unroll
            for (int nt = 0; nt < 4; nt++) {
                const int c = ce0 + nt * 16;
                const float bv = ldx(bias, c, inf32);
#pragma unroll
                for (int i = 0; i < 4; i++) {
                    const int r = re0 + mt * 16 + i;
                    Qo[((size_t)a_row0 + r) * 1024 + c] =
                        f2bf((acc[mt][nt][i] + bv) * 0.125f);
                }
            }
    } else if (n0 < 2048) {
#pragma unroll
        for (int mt = 0; mt < 4; mt++)
#pragma unroll
            for (int nt = 0; nt < 4; nt++) {
                const int c = ce0 + nt * 16;
                const float bv = ldx(bias, c, inf32);
#pragma unroll
                for (int i = 0; i < 4; i++) {
                    const int r = re0 + mt * 16 + i;
                    Ko[(size_t)r * 1024 + (c - 1024)] = f2bf(acc[mt][nt][i] + bv);
                }
            }
    } else {
#pragma unroll
        for (int mt = 0; mt < 4; mt++)
#pragma unroll
            for (int nt = 0; nt < 4; nt++) {
                const int c = ce0 + nt * 16;
                const float bv = ldx(bias, c, inf32);
                const int cv = c - 2048;
                const int hh = cv >> 6, d = cv & 63;
                const int rb = re0 + mt * 16;
                const int bl = rb >> 10, t = rb & 1023;
                short4v pk;
#pragma unroll
                for (int i = 0; i < 4; i++)
                    pk[i] = (short)f2bf(acc[mt][nt][i] + bv);
                *(short4v*)&Vt[((size_t)(bl * 16 + hh) * 64 + d) * 1024 + t] = pk;
            }
    }
}

// fc2 K-chunk accumulating into fp32 (tier C only)
__global__ __launch_bounds__(256, 2) void gemm_accf32(
    const void* __restrict__ A, const void* __restrict__ W, long w_off,
    const void* __restrict__ bias, const u16* __restrict__ resid, long r_row0,
    float* __restrict__ C, int ldw, int init, const int* __restrict__ flags)
{
    GEMM_CORE(A, 0, 0, W, w_off, ldw, 1024)
#pragma unroll
    for (int mt = 0; mt < 4; mt++) {
#pragma unroll
        for (int nt = 0; nt < 4; nt++) {
            const int c = ce0 + nt * 16;
            const float bv = ldx(bias, c, inf32);
#pragma unroll
            for (int i = 0; i < 4; i++) {
                const int r = re0 + mt * 16 + i;
                float v = acc[mt][nt][i];
                if (init) v += bv + bf2f(resid[((size_t)r_row0 + r) * 1024 + c]);
                else      v += C[(size_t)r * 1024 + c];
                C[(size_t)r * 1024 + c] = v;
            }
        }
    }
}

// ---------------------------------------------------------------------------
// gemm8: 128x256 tile, BK=64, 512 threads = 8 waves (2M x 4N), per-wave 64x64.
// Triple-buffered LDS (144 KiB): tile t reads buf t%3; tile t+2 staged into
// buf (t+2)%3 during tile t (free since t-1's reads drained at its barrier).
// Per K-tile: 2 phases {8 ds_read_b128 || stage -> barrier -> lgkmcnt(0) ->
// setprio(1) -> 16 MFMA -> setprio(0) -> barrier}; end-of-tile vmcnt(6)
// leaves exactly tile t+2's 6 loads in flight -> loads have a full tile
// (>1500 cyc) to land, covering HBM latency.
// Swizzle: 16B chunk ch ^= row&7 on both the pre-swizzled global source of
// global_load_lds (linear LDS dest) and the ds_read address; frag reads are
// ~2-way (free).
// ---------------------------------------------------------------------------
#define GEMM8_PRE(Ag_, Wg_, Kg_)                                              \
    __shared__ __align__(16) u16 Ab[3][128 * 64];                             \
    __shared__ __align__(16) u16 Bb[3][256 * 64];                             \
    const u16* Ag = (Ag_); const u16* Wg = (Wg_); const int Kg = (Kg_);       \
    const int tid  = threadIdx.x;                                             \
    const int lane = tid & 63;                                                \
    const int lc   = lane & 15;                                               \
    const int quad = lane >> 4;                                               \
    const int w    = tid >> 6;                                                \
    const int wr   = w >> 2;                                                  \
    const int wc   = w & 3;                                                   \
    const int m0 = blockIdx.x * 128;                                          \
    const int n0 = blockIdx.y * 256;                                          \
    const int srow = tid >> 3;                                                \
    const int scol = (((tid & 7) ^ (srow & 7)) << 3);                         \
    const int sw0 = (((quad) ^ (lc & 7)) << 3);                               \
    const int sw1 = sw0 ^ 32;                                                 \
    f32x4 acc[4][4] = {};                                                     \
    short8 af[4], bf[4];

#define SA8(buf, kk) do {                                                     \
    GLD16(Ag + (size_t)(m0 + srow) * Kg + (kk) + scol, &Ab[buf][tid * 8]);    \
    GLD16(Ag + (size_t)(m0 + 64 + srow) * Kg + (kk) + scol,                   \
          &Ab[buf][4096 + tid * 8]); } while (0)
#define SB8a(buf, kk) do {                                                    \
    GLD16(Wg + (size_t)(n0 + srow) * Kg + (kk) + scol, &Bb[buf][tid * 8]);    \
    GLD16(Wg + (size_t)(n0 + 64 + srow) * Kg + (kk) + scol,                   \
          &Bb[buf][4096 + tid * 8]); } while (0)
#define SB8b(buf, kk) do {                                                    \
    GLD16(Wg + (size_t)(n0 + 128 + srow) * Kg + (kk) + scol,                  \
          &Bb[buf][8192 + tid * 8]);                                          \
    GLD16(Wg + (size_t)(n0 + 192 + srow) * Kg + (kk) + scol,                  \
          &Bb[buf][12288 + tid * 8]); } while (0)
#define LDFR(rbuf, SW) do { _Pragma("unroll")                                 \
    for (int q_ = 0; q_ < 4; q_++) {                                          \
        af[q_] = *(const short8*)&Ab[rbuf][(wr * 64 + q_ * 16 + lc) * 64 + (SW)];\
        bf[q_] = *(const short8*)&Bb[rbuf][(wc * 64 + q_ * 16 + lc) * 64 + (SW)];\
    } } while (0)
#define MFMA16 do { _Pragma("unroll")                                         \
    for (int mq = 0; mq < 4; mq++) { _Pragma("unroll")                        \
    for (int nq = 0; nq < 4; nq++)                                            \
        acc[mq][nq] = __builtin_amdgcn_mfma_f32_16x16x32_bf16(                \
            af[mq], bf[nq], acc[mq][nq], 0, 0, 0); } } while (0)

#define GEMM8_LOOP                                                            \
    const int NT = Kg >> 6;                                                   \
    SA8(0, 0); SB8a(0, 0); SB8b(0, 0);                                        \
    if (NT > 1) { SA8(1, 64); SB8a(1, 64); SB8b(1, 64); }                     \
    if (NT > 1) asm volatile("s_waitcnt vmcnt(6)" ::: "memory");              \
    else        asm volatile("s_waitcnt vmcnt(0)" ::: "memory");              \
    __builtin_amdgcn_s_barrier();                                             \
    int rb_ = 0, wb_ = 2;                                                     \
    for (int t = 0; t < NT; ++t) {                                            \
        const bool s_ = (t + 2 < NT);                                         \
        const int k2_ = (t + 2) << 6;                                         \
        LDFR(rb_, sw0);                                                       \
        if (s_) { SA8(wb_, k2_); SB8a(wb_, k2_); }                            \
        __builtin_amdgcn_s_barrier();                                         \
        asm volatile("s_waitcnt lgkmcnt(0)" ::: "memory");                    \
        __builtin_amdgcn_s_setprio(1);                                        \
        MFMA16;                                                               \
        __builtin_amdgcn_s_setprio(0);                                        \
        __builtin_amdgcn_s_barrier();                                         \
        LDFR(rb_, sw1);                                                       \
        if (s_) SB8b(wb_, k2_);                                               \
        __builtin_amdgcn_s_barrier();                                         \
        asm volatile("s_waitcnt lgkmcnt(0)" ::: "memory");                    \
        __builtin_amdgcn_s_setprio(1);                                        \
        MFMA16;                                                               \
        __builtin_amdgcn_s_setprio(0);                                        \
        if (s_) asm volatile("s_waitcnt vmcnt(6)" ::: "memory");              \
        else    asm volatile("s_waitcnt vmcnt(0)" ::: "memory");              \
        __builtin_amdgcn_s_barrier();                                         \
        rb_ = (rb_ == 2) ? 0 : rb_ + 1;                                       \
        wb_ = (wb_ == 2) ? 0 : wb_ + 1;                                       \
    }                                                                         \
    const int cb0 = n0 + wc * 64 + lc;                                        \
    const int rb0 = m0 + wr * 64 + quad * 4;

// Generic: C = A @ W^T + bias (+resid EPI=1, relu EPI=2). All bf16.
template<int EPI>
__global__ __launch_bounds__(512, 2) void gemm8(
    const u16* __restrict__ A, const u16* __restrict__ W,
    const u16* __restrict__ bias, const u16* __restrict__ resid,
    u16* __restrict__ C, int N, int K)
{
    GEMM8_PRE(A, W, K)
    GEMM8_LOOP
#pragma unroll
    for (int mq = 0; mq < 4; mq++) {
#pragma unroll
        for (int nq = 0; nq < 4; nq++) {
            const int cN = cb0 + nq * 16;
            const float bv = bf2f(bias[cN]);
#pragma unroll
            for (int i = 0; i < 4; i++) {
                const int rM = rb0 + mq * 16 + i;
                float v = acc[mq][nq][i] + bv;
                if (EPI == 1) v += bf2f(resid[(size_t)rM * N + cN]);
                if (EPI == 2) v = fmaxf(v, 0.0f);
                C[(size_t)rM * N + cN] = f2bf(v);
            }
        }
    }
}

// QKV on the gemm8 core (tier A): N=3072, K=1024. n0 block-uniform branch.
__global__ __launch_bounds__(512, 2) void gemm8_qkv(
    const u16* __restrict__ A, const u16* __restrict__ W,
    const u16* __restrict__ bias,
    u16* __restrict__ Qo, u16* __restrict__ Ko, u16* __restrict__ Vt)
{
    GEMM8_PRE(A, W, 1024)
    GEMM8_LOOP
    if (n0 < 1024) {
#pragma unroll
        for (int mq = 0; mq < 4; mq++)
#pragma unroll
            for (int nq = 0; nq < 4; nq++) {
                const int c = cb0 + nq * 16;
                const float bv = bf2f(bias[c]);
#pragma unroll
                for (int i = 0; i < 4; i++) {
                    const int r = rb0 + mq * 16 + i;
                    Qo[(size_t)r * 1024 + c] =
                        f2bf((acc[mq][nq][i] + bv) * 0.125f);
                }
            }
    } else if (n0 < 2048) {
#pragma unroll
        for (int mq = 0; mq < 4; mq++)
#pragma unroll
            for (int nq = 0; nq < 4; nq++) {
                const int c = cb0 + nq * 16;
                const float bv = bf2f(bias[c]);
#pragma unroll
                for (int i = 0; i < 4; i++) {
                    const int r = rb0 + mq * 16 + i;
                    Ko[(size_t)r * 1024 + (c - 1024)] =
                        f2bf(acc[mq][nq][i] + bv);
                }
            }
    } else {
#pragma unroll
        for (int mq = 0; mq < 4; mq++)
#pragma unroll
            for (int nq = 0; nq < 4; nq++) {
                const int c = cb0 + nq * 16;
                const float bv = bf2f(bias[c]);
                const int cv = c - 2048;
                const int hh = cv >> 6, d = cv & 63;
                const int rbase = rb0 + mq * 16;
                const int bl = rbase >> 10, tt = rbase & 1023;
                short4v pk;
#pragma unroll
                for (int i = 0; i < 4; i++)
                    pk[i] = (short)f2bf(acc[mq][nq][i] + bv);
                *(short4v*)&Vt[((size_t)(bl * 16 + hh) * 64 + d) * 1024 + tt] = pk;
            }
    }
}

// ---------------------------------------------------------------------------
// Flash attention v3: paired q-tiles (qt, 7-qt) of 128 rows -> uniform 18
// k-tile units/block. Double-buffered K/V staging. Grid (4, nbh).
// ---------------------------------------------------------------------------
__global__ __launch_bounds__(256, 2) void attn_kernel(
    u16* __restrict__ QO, const u16* __restrict__ Ko,
    const u16* __restrict__ Vt, const float* __restrict__ kb, int b0)
{
    __shared__ __align__(16) u16 Qs[2 * 128 * 32];   // [kcd][qrow][32]
    __shared__ __align__(16) u16 Ks[2][2 * 64 * 32]; // dbuf [kcd][key][32]
    __shared__ __align__(16) u16 Vs[2][2 * 64 * 32]; // dbuf [kck][d][32]
    __shared__ __align__(16) u16 Ps[4][32 * 72];
    __shared__ float kba[1024];

    const int tid  = threadIdx.x;
    const int lane = tid & 63;
    const int w    = tid >> 6;
    const int lc   = lane & 15;
    const int quad = lane >> 4;
    const int bl = blockIdx.y >> 4;
    const int h  = blockIdx.y & 15;
    const int b  = b0 + bl;

    // preload padding-bias column for this sequence
    *(f32x4*)&kba[tid * 4] = *(const f32x4*)&kb[b * 1024 + tid * 4];

    for (int p = 0; p < 2; p++) {
        const int qt = p ? 7 - (int)blockIdx.x : (int)blockIdx.x;

        // stage Q tile [kcd][128][32]
#pragma unroll
        for (int it = 0; it < 4; it++) {
            const int kcd = it >> 1, half = it & 1;
            const int r = half * 64 + (tid >> 2);
            const int c = kcd * 32 + (tid & 3) * 8;
            GLD16(&QO[((size_t)(b * 1024 + qt * 128 + r)) * 1024 + h * 64 + c],
                  &Qs[kcd * 4096 + half * 2048 + tid * 8]);
        }
        // stage kt=0 into buffer 0
        {
            const int rr = tid >> 2;
#pragma unroll
            for (int it = 0; it < 2; it++) {
                const int cc = it * 32 + (tid & 3) * 8;
                GLD16(&Ko[((size_t)(bl * 1024 + rr)) * 1024 + h * 64 + cc],
                      &Ks[0][it * 2048 + tid * 8]);
                GLD16(&Vt[((size_t)(bl * 16 + h) * 64 + rr) * 1024 + cc],
                      &Vs[0][it * 2048 + tid * 8]);
            }
        }
        __syncthreads();   // Q + K0/V0 (+ kba on p=0) ready

        short8 aq[2][2];
#pragma unroll
        for (int mt = 0; mt < 2; mt++)
#pragma unroll
            for (int kc = 0; kc < 2; kc++)
                aq[mt][kc] = *(const short8*)
                    &Qs[kc * 4096 + (w * 32 + mt * 16 + lc) * 32 + quad * 8];

        f32x4 o[2][4] = {};
        float m_i[2][4], l_i[2][4];
#pragma unroll
        for (int mt = 0; mt < 2; mt++)
#pragma unroll
            for (int i = 0; i < 4; i++) { m_i[mt][i] = -1e30f; l_i[mt][i] = 0.0f; }

        const int ktmax = 2 * qt + 2;
        for (int kt = 0; kt < ktmax; kt++) {
            const int cur = kt & 1;
            // prefetch kt+1 (overlaps with compute below; drained at barrier)
            if (kt + 1 < ktmax) {
                const int nxt = cur ^ 1;
                const int rr = tid >> 2;
#pragma unroll
                for (int it = 0; it < 2; it++) {
                    const int cc = it * 32 + (tid & 3) * 8;
                    GLD16(&Ko[((size_t)(bl * 1024 + (kt + 1) * 64 + rr)) * 1024 + h * 64 + cc],
                          &Ks[nxt][it * 2048 + tid * 8]);
                    GLD16(&Vt[((size_t)(bl * 16 + h) * 64 + rr) * 1024 + (kt + 1) * 64 + cc],
                          &Vs[nxt][it * 2048 + tid * 8]);
                }
            }

            // S = Q K^T
            short8 bk[4][2];
#pragma unroll
            for (int nt = 0; nt < 4; nt++)
#pragma unroll
                for (int kc = 0; kc < 2; kc++)
                    bk[nt][kc] = *(const short8*)
                        &Ks[cur][kc * 2048 + (nt * 16 + lc) * 32 + quad * 8];

            f32x4 s[2][4];
#pragma unroll
            for (int mt = 0; mt < 2; mt++)
#pragma unroll
                for (int nt = 0; nt < 4; nt++) {
                    f32x4 z = {};
#pragma unroll
                    for (int kc = 0; kc < 2; kc++)
                        z = __builtin_amdgcn_mfma_f32_16x16x32_bf16(
                            aq[mt][kc], bk[nt][kc], z, 0, 0, 0);
                    s[mt][nt] = z;
                }

            const int causal = (kt >= 2 * qt);   // block-uniform
            float al[2][4];
#pragma unroll
            for (int mt = 0; mt < 2; mt++) {
                const int qg0 = qt * 128 + w * 32 + mt * 16 + quad * 4;
#pragma unroll
                for (int nt = 0; nt < 4; nt++) {
                    const int kg = kt * 64 + nt * 16 + lc;
                    const float kbv = kba[kt * 64 + nt * 16 + lc];
#pragma unroll
                    for (int i = 0; i < 4; i++) {
                        float sv = s[mt][nt][i] + kbv;
                        if (causal && kg > qg0 + i) sv = -1e30f;
                        s[mt][nt][i] = sv;
                    }
                }
                float mnew[4], rs[4];
#pragma unroll
                for (int i = 0; i < 4; i++) {
                    float rm = fmaxf(fmaxf(s[mt][0][i], s[mt][1][i]),
                                     fmaxf(s[mt][2][i], s[mt][3][i]));
                    rm = fmaxf(rm, __shfl_xor(rm, 1));
                    rm = fmaxf(rm, __shfl_xor(rm, 2));
                    rm = fmaxf(rm, __shfl_xor(rm, 4));
                    rm = fmaxf(rm, __shfl_xor(rm, 8));
                    mnew[i] = fmaxf(m_i[mt][i], rm);
                    al[mt][i] = exp2f((m_i[mt][i] - mnew[i]) * 1.442695041f);
                    rs[i] = 0.0f;
                }
#pragma unroll
                for (int nt = 0; nt < 4; nt++)
#pragma unroll
                    for (int i = 0; i < 4; i++) {
                        float pp = exp2f((s[mt][nt][i] - mnew[i]) * 1.442695041f);
                        s[mt][nt][i] = pp;
                        rs[i] += pp;
                    }
#pragma unroll
                for (int i = 0; i < 4; i++) {
                    float r = rs[i];
                    r += __shfl_xor(r, 1);
                    r += __shfl_xor(r, 2);
                    r += __shfl_xor(r, 4);
                    r += __shfl_xor(r, 8);
                    l_i[mt][i] = l_i[mt][i] * al[mt][i] + r;
                    m_i[mt][i] = mnew[i];
                }
#pragma unroll
                for (int nt = 0; nt < 4; nt++)
#pragma unroll
                    for (int i = 0; i < 4; i++)
                        Ps[w][(mt * 16 + quad * 4 + i) * 72 + nt * 16 + lc] =
                            f2bf(s[mt][nt][i]);
            }

            // O = O*alpha + P @ V
            short8 ap[2][2], bv2[4][2];
#pragma unroll
            for (int mt = 0; mt < 2; mt++)
#pragma unroll
                for (int kc = 0; kc < 2; kc++)
                    ap[mt][kc] = *(const short8*)
                        &Ps[w][(mt * 16 + lc) * 72 + kc * 32 + quad * 8];
#pragma unroll
            for (int nt = 0; nt < 4; nt++)
#pragma unroll
                for (int kc = 0; kc < 2; kc++)
                    bv2[nt][kc] = *(const short8*)
                        &Vs[cur][kc * 2048 + (nt * 16 + lc) * 32 + quad * 8];
#pragma unroll
            for (int mt = 0; mt < 2; mt++)
#pragma unroll
                for (int nt = 0; nt < 4; nt++) {
                    f32x4 oo = o[mt][nt];
#pragma unroll
                    for (int i = 0; i < 4; i++) oo[i] *= al[mt][i];
#pragma unroll
                    for (int kc = 0; kc < 2; kc++)
                        oo = __builtin_amdgcn_mfma_f32_16x16x32_bf16(
                            ap[mt][kc], bv2[nt][kc], oo, 0, 0, 0);
                    o[mt][nt] = oo;
                }
            __syncthreads();   // prefetch drained; buffers safe to swap
        }

        // write O in place of Q (exclusive slice)
#pragma unroll
        for (int mt = 0; mt < 2; mt++)
#pragma unroll
            for (int i = 0; i < 4; i++) {
                const float inv = l_i[mt][i] > 0.0f ? 1.0f / l_i[mt][i] : 0.0f;
#pragma unroll
                for (int nt = 0; nt < 4; nt++) {
                    const int r = qt * 128 + w * 32 + mt * 16 + quad * 4 + i;
                    const int d = nt * 16 + lc;
                    QO[((size_t)(b * 1024 + r)) * 1024 + h * 64 + d] =
                        f2bf(o[mt][nt][i] * inv);
                }
            }
    }
}

// ---------------------------------------------------------------------------
// LayerNorm, one block/row, biased variance, eps=1e-12.
// ---------------------------------------------------------------------------
template<int IN16, int OUTSEL>
__global__ __launch_bounds__(256) void ln_kernel(
    const void* __restrict__ yv, const void* __restrict__ w,
    const void* __restrict__ bb, void* __restrict__ o, long o_row0,
    const int* __restrict__ flags)
{
    const int row = blockIdx.x;
    const int tid = threadIdx.x;
    const int inf32 = flags[0];
    float x0, x1, x2, x3;
    if (IN16) {
        const u16* p = (const u16*)yv + (size_t)row * 1024 + tid * 4;
        short4v v = *(const short4v*)p;
        x0 = bf2f((u16)v[0]); x1 = bf2f((u16)v[1]);
        x2 = bf2f((u16)v[2]); x3 = bf2f((u16)v[3]);
    } else {
        const float* p = (const float*)yv + (size_t)row * 1024 + tid * 4;
        f32x4 v = *(const f32x4*)p;
        x0 = v[0]; x1 = v[1]; x2 = v[2]; x3 = v[3];
    }
    float s = x0 + x1 + x2 + x3;
    float q = x0 * x0 + x1 * x1 + x2 * x2 + x3 * x3;
#pragma unroll
    for (int off = 32; off; off >>= 1) {
        s += __shfl_xor(s, off);
        q += __shfl_xor(q, off);
    }
    __shared__ float sm[8];
    const int lane = tid & 63, wv = tid >> 6;
    if (lane == 0) { sm[wv] = s; sm[4 + wv] = q; }
    __syncthreads();
    const float ts = sm[0] + sm[1] + sm[2] + sm[3];
    const float tq = sm[4] + sm[5] + sm[6] + sm[7];
    const float mean = ts * (1.0f / 1024.0f);
    float var = tq * (1.0f / 1024.0f) - mean * mean;
    if (var < 0.0f) var = 0.0f;
    const float rinv = rsqrtf(var + 1e-12f);

    const size_t obase = ((size_t)o_row0 + row) * 1024 + tid * 4;
#pragma unroll
    for (int j = 0; j < 4; j++) {
        const int c = tid * 4 + j;
        float xv = (j == 0) ? x0 : (j == 1) ? x1 : (j == 2) ? x2 : x3;
        float v = ldx(w, c, inf32) * ((xv - mean) * rinv) + ldx(bb, c, inf32);
        if (OUTSEL && inf32) ((float*)o)[obase + j] = v;
        else                 ((u16*)o)[obase + j] = f2bf(v);
    }
}

// ---------------------------------------------------------------------------
extern "C" void kernel_launch(void* const* d_in, const int* in_sizes, int n_in,
                              void* d_out, int out_size, void* d_ws, size_t ws_size,
                              hipStream_t stream)
{
    const void* x     = d_in[0];
    const void* in_w  = d_in[1];
    const void* in_b  = d_in[2];
    const void* out_w = d_in[3];
    const void* out_b = d_in[4];
    const void* fc1_w = d_in[5];
    const void* fc1_b = d_in[6];
    const void* fc2_w = d_in[7];
    const void* fc2_b = d_in[8];
    const void* ln1w  = d_in[9];
    const void* ln1b  = d_in[10];
    const void* ln2w  = d_in[11];
    const void* ln2b  = d_in[12];
    const void* pad   = d_in[13];
    u16* outp = (u16*)d_out;
    char* ws = (char*)d_ws;
    dim3 blk(256);
    dim3 blk8(512);

    const size_t MB = 1024 * 1024;
    const bool bigWS = ws_size >= (105 * MB + 64 * 1024);

    if (bigWS) {
        // Tier A layout:
        //  0-16  xb -> x1        16-22 w1b (dead after qkv) \
        //  22-24 wob (dead after proj)  24-32 f1b (dead after fc1) } -> y2 16-32
        //  32-40 f2b   40-41 biases     41-57 Ko    57-73 Vt
        //  73-89 y1    41-105 h (FF)    105+ flags / kbias
        u16*   xb   = (u16*)(ws + 0);
        u16*   x1   = (u16*)(ws + 0);
        u16*   w1b  = (u16*)(ws + 16 * MB);
        u16*   wob  = (u16*)(ws + 22 * MB);
        u16*   f1b  = (u16*)(ws + 24 * MB);
        u16*   f2b  = (u16*)(ws + 32 * MB);
        u16*   inbb = (u16*)(ws + 40 * MB);
        u16*   outbb= (u16*)(ws + 40 * MB + 8192);
        u16*   f1bb = (u16*)(ws + 40 * MB + 16384);
        u16*   f2bb = (u16*)(ws + 40 * MB + 24576);
        u16*   Ko   = (u16*)(ws + 41 * MB);
        u16*   Vt   = (u16*)(ws + 57 * MB);
        u16*   y1   = (u16*)(ws + 73 * MB);
        u16*   h    = (u16*)(ws + 41 * MB);
        u16*   y2   = (u16*)(ws + 16 * MB);
        int*   flags  = (int*)(ws + 105 * MB);
        int*   flagsA = (int*)(ws + 105 * MB + 32);
        float* kbias  = (float*)(ws + 105 * MB + 64);

        probe_kernel<<<dim3(1), dim3(64), 0, stream>>>(x, pad, flags, flagsA);
        mask_to_bias<<<dim3(32), blk, 0, stream>>>(pad, kbias, flags);
        conv4<<<dim3(8192), blk, 0, stream>>>(x, xb, 2097152, flags);
        conv4<<<dim3(3072), blk, 0, stream>>>(in_w, w1b, 786432, flags);
        conv4<<<dim3(1024), blk, 0, stream>>>(out_w, wob, 262144, flags);
        conv4<<<dim3(4096), blk, 0, stream>>>(fc1_w, f1b, 1048576, flags);
        conv4<<<dim3(4096), blk, 0, stream>>>(fc2_w, f2b, 1048576, flags);
        conv4<<<dim3(3), blk, 0, stream>>>(in_b, inbb, 768, flags);
        conv4<<<dim3(1), blk, 0, stream>>>(out_b, outbb, 256, flags);
        conv4<<<dim3(4), blk, 0, stream>>>(fc1_b, f1bb, 1024, flags);
        conv4<<<dim3(1), blk, 0, stream>>>(fc2_b, f2bb, 256, flags);

        // qkv on the gemm8 core: [8192,3072] K=1024
        gemm8_qkv<<<dim3(64, 12), blk8, 0, stream>>>(
            xb, w1b, inbb, outp, Ko, Vt);
        attn_kernel<<<dim3(4, 128), blk, 0, stream>>>(outp, Ko, Vt, kbias, 0);
        // out-proj: y1 = attn @ wob^T + outbb + xb   [8192,1024] K=1024
        gemm8<1><<<dim3(64, 4), blk8, 0, stream>>>(
            outp, wob, outbb, xb, y1, 1024, 1024);
        ln_kernel<1, 0><<<dim3(8192), blk, 0, stream>>>(y1, ln1w, ln1b, x1, 0, flags);
        // fc1: h = relu(x1 @ f1b^T + f1bb)   [8192,4096] K=1024
        gemm8<2><<<dim3(64, 16), blk8, 0, stream>>>(
            x1, f1b, f1bb, nullptr, h, 4096, 1024);
        // fc2: y2 = h @ f2b^T + f2bb + x1    [8192,1024] K=4096
        gemm8<1><<<dim3(64, 4), blk8, 0, stream>>>(
            h, f2b, f2bb, x1, y2, 1024, 4096);
        ln_kernel<1, 1><<<dim3(8192), blk, 0, stream>>>(y2, ln2w, ln2b, d_out, 0, flags);
    } else {
        // Tier C: quartered, 12.6 MB workspace
        u16*   Ko    = (u16*)(ws + 0);
        u16*   Vt    = (u16*)(ws + 4 * MB);
        u16*   y1h   = (u16*)(ws + 0);
        float* acc   = (float*)(ws + 0);
        u16*   hc    = (u16*)(ws + 8 * MB);
        int*   flags  = (int*)(ws + 12 * MB);
        int*   flagsA = (int*)(ws + 12 * MB + 32);
        float* kbias  = (float*)(ws + 12 * MB + 64);

        probe_kernel<<<dim3(1), dim3(64), 0, stream>>>(x, pad, flags, flagsA);
        mask_to_bias<<<dim3(32), blk, 0, stream>>>(pad, kbias, flags);

        for (int q = 0; q < 4; q++) {
            const long r0 = (long)q * 2048;
            gemm_qkv<<<dim3(16, 24), blk, 0, stream>>>(
                x, r0, in_w, in_b, outp, Ko, Vt, flags);
            attn_kernel<<<dim3(4, 32), blk, 0, stream>>>(
                outp, Ko, Vt, kbias, q * 2);
        }
        for (int hf = 0; hf < 2; hf++) {
            const long r0 = (long)hf * 4096;
            gemm_bt<1><<<dim3(32, 8), blk, 0, stream>>>(
                outp, 0, r0, out_w, 0, out_b, 0, x, 1, r0,
                y1h, 0, 1024, 1024, 1024, flags);
            ln_kernel<1, 0><<<dim3(4096), blk, 0, stream>>>(
                y1h, ln1w, ln1b, outp, r0, flags);
        }
        for (int q = 3; q >= 0; q--) {
            const long r0 = (long)q * 2048;
            for (int c = 0; c < 4; c++) {
                gemm_bt<2><<<dim3(16, 8), blk, 0, stream>>>(
                    outp, 0, r0, fc1_w, (long)c * 1024 * 1024, fc1_b, (long)c * 1024,
                    nullptr, 0, 0, hc, 0, 1024, 1024, 1024, flags);
                gemm_accf32<<<dim3(16, 8), blk, 0, stream>>>(
                    hc, fc2_w, (long)c * 1024, fc2_b, outp, r0,
                    acc, 4096, c == 0, flags);
            }
            ln_kernel<0, 1><<<dim3(2048), blk, 0, stream>>>(
                acc, ln2w, ln2b, d_out, r0, flags);
        }
    }
}

// Round 4
// 524.201 us; speedup vs baseline: 1.1660x; 1.0143x over previous
//
#include <hip/hip_runtime.h>

typedef unsigned short u16;
typedef __attribute__((ext_vector_type(8))) short short8;
typedef __attribute__((ext_vector_type(4))) short short4v;
typedef __attribute__((ext_vector_type(4))) float f32x4;

#define DEV static __device__ __forceinline__

DEV float bf2f(u16 h) {
    union { unsigned int u; float f; } v; v.u = ((unsigned int)h) << 16; return v.f;
}
DEV u16 f2bf(float f) {
    union { float f; unsigned int u; } v; v.f = f;
    unsigned int r = (v.u + 0x7fff + ((v.u >> 16) & 1)) >> 16;
    return (u16)r;
}
DEV float ldx(const void* p, size_t i, int f32) {
    return f32 ? ((const float*)p)[i] : bf2f(((const u16*)p)[i]);
}

#define GLD16(g, l) __builtin_amdgcn_global_load_lds( \
    (const __attribute__((address_space(1))) void*)(g), \
    (__attribute__((address_space(3))) void*)(l), 16, 0, 0)

#define STAGE(P, pf32, eoff, dst8) do {                                        \
    if (!(pf32)) { GLD16(((const u16*)(P)) + (eoff), (dst8)); }                \
    else {                                                                     \
        const float* _p = ((const float*)(P)) + (eoff);                        \
        f32x4 _a = *(const f32x4*)_p, _b = *(const f32x4*)(_p + 4);            \
        short8 _s;                                                             \
        _s[0]=(short)f2bf(_a[0]); _s[1]=(short)f2bf(_a[1]);                    \
        _s[2]=(short)f2bf(_a[2]); _s[3]=(short)f2bf(_a[3]);                    \
        _s[4]=(short)f2bf(_b[0]); _s[5]=(short)f2bf(_b[1]);                    \
        _s[6]=(short)f2bf(_b[2]); _s[7]=(short)f2bf(_b[3]);                    \
        *(short8*)(dst8) = _s;                                                 \
    } } while (0)

// ---------------------------------------------------------------------------
// Probe: flags[0]=1 -> inputs fp32; flags[1]=1 -> mask is bool bytes.
// ---------------------------------------------------------------------------
__global__ __launch_bounds__(64) void probe_kernel(
    const void* __restrict__ x, const void* __restrict__ pad,
    int* __restrict__ flags, int* __restrict__ flagsA)
{
    const int lane = threadIdx.x;
    const u16* xu = (const u16*)x;
    const unsigned int e = (xu[lane * 2] >> 7) & 0xFF;
    const int sane = (e >= 0x70 && e <= 0x8F) ? 1 : 0;
    unsigned long long m = __ballot(sane);
    const int f32 = (__popcll(m) < 32) ? 1 : 0;

    const unsigned int* pi = (const unsigned int*)pad;
    int bytes = 0;
#pragma unroll
    for (int j = 0; j < 6; j++) {
        unsigned int v = pi[128 + j * 64 + lane];
        if (v > 1u) bytes = 1;
    }
    m = __ballot(bytes);
    if (lane == 0) {
        flags[0] = f32; flags[1] = (m != 0ULL) ? 1 : 0;
        flagsA[0] = 0;  flagsA[1] = 0;
    }
}

__global__ __launch_bounds__(256) void conv4(
    const void* __restrict__ src, u16* __restrict__ dst, int n4,
    const int* __restrict__ flags)
{
    const int i = blockIdx.x * 256 + threadIdx.x;
    if (i >= n4) return;
    if (flags[0]) {
        f32x4 v = ((const f32x4*)src)[i];
        short4v s;
        s[0] = (short)f2bf(v[0]); s[1] = (short)f2bf(v[1]);
        s[2] = (short)f2bf(v[2]); s[3] = (short)f2bf(v[3]);
        ((short4v*)dst)[i] = s;
    } else {
        ((short4v*)dst)[i] = ((const short4v*)src)[i];
    }
}

__global__ __launch_bounds__(256) void mask_to_bias(
    const void* __restrict__ pad, float* __restrict__ out,
    const int* __restrict__ flags)
{
    const int i = blockIdx.x * 256 + threadIdx.x;
    const int mv = flags[1] ? (int)((const unsigned char*)pad)[i]
                            : ((const int*)pad)[i];
    out[i] = mv ? -1e30f : 0.0f;
}

// ---------------------------------------------------------------------------
// Shared GEMM core: 128x128 tile, BK=32, 256 threads (4 waves, 4x4 mfma each).
// (retained for tier C)
// ---------------------------------------------------------------------------
#define GEMM_CORE(Av, ASEL, a_row0, Wv, w_off, ldw, K)                        \
    __shared__ __align__(16) u16 As[128 * 32];                                \
    __shared__ __align__(16) u16 Bs[128 * 32];                                \
    const int inf32 = flags[0];                                               \
    const int af32  = (ASEL) ? inf32 : 0;                                     \
    const int tid  = threadIdx.x;                                             \
    const int lane = tid & 63;                                                \
    const int wave = tid >> 6;                                                \
    const int lc   = lane & 15;                                               \
    const int quad = lane >> 4;                                               \
    const int m0 = blockIdx.x * 128;                                          \
    const int n0 = blockIdx.y * 128;                                          \
    const int wm = (wave >> 1) * 64;                                          \
    const int wn = (wave & 1) * 64;                                           \
    const int r0 = tid >> 2;                                                  \
    const int ko = (tid & 3) * 8;                                             \
    f32x4 acc[4][4] = {};                                                     \
    for (int k0 = 0; k0 < (K); k0 += 32) {                                    \
        STAGE(Av, af32, ((size_t)(a_row0) + m0 + r0) * (K) + k0 + ko,         \
              &As[tid * 8]);                                                  \
        STAGE(Av, af32, ((size_t)(a_row0) + m0 + r0 + 64) * (K) + k0 + ko,    \
              &As[2048 + tid * 8]);                                           \
        STAGE(Wv, inf32, (size_t)(w_off) + (size_t)(n0 + r0) * (ldw) + k0 + ko,\
              &Bs[tid * 8]);                                                  \
        STAGE(Wv, inf32, (size_t)(w_off) + (size_t)(n0 + r0 + 64) * (ldw) + k0 + ko,\
              &Bs[2048 + tid * 8]);                                           \
        __syncthreads();                                                      \
        short8 afr[4], bfr[4];                                                \
        const int qd = quad * 8;                                              \
        _Pragma("unroll")                                                     \
        for (int mt = 0; mt < 4; mt++)                                        \
            afr[mt] = *(const short8*)&As[(wm + mt * 16 + lc) * 32 + qd];     \
        _Pragma("unroll")                                                     \
        for (int nt = 0; nt < 4; nt++)                                        \
            bfr[nt] = *(const short8*)&Bs[(wn + nt * 16 + lc) * 32 + qd];     \
        _Pragma("unroll")                                                     \
        for (int mt = 0; mt < 4; mt++)                                        \
            _Pragma("unroll")                                                 \
            for (int nt = 0; nt < 4; nt++)                                    \
                acc[mt][nt] = __builtin_amdgcn_mfma_f32_16x16x32_bf16(        \
                    afr[mt], bfr[nt], acc[mt][nt], 0, 0, 0);                  \
        __syncthreads();                                                      \
    }                                                                         \
    const int ce0 = n0 + wn + lc;                                             \
    const int re0 = m0 + wm + quad * 4;

// Generic GEMM: C = A @ W^T + bias.  EPI: 0 bias, 1 +resid, 2 +relu.
template<int EPI>
__global__ __launch_bounds__(256, 2) void gemm_bt(
    const void* __restrict__ A, int a_sel, long a_row0,
    const void* __restrict__ W, long w_off,
    const void* __restrict__ bias, long b_off,
    const void* __restrict__ resid, int r_sel, long r_row0,
    u16* __restrict__ C, long c_row0,
    int N, int K, int ldw, const int* __restrict__ flags)
{
    GEMM_CORE(A, a_sel, a_row0, W, w_off, ldw, K)
    const int rf32 = r_sel ? inf32 : 0;
#pragma unroll
    for (int mt = 0; mt < 4; mt++) {
#pragma unroll
        for (int nt = 0; nt < 4; nt++) {
            const int c = ce0 + nt * 16;
            const float bv = ldx(bias, (size_t)b_off + c, inf32);
#pragma unroll
            for (int i = 0; i < 4; i++) {
                const int r = re0 + mt * 16 + i;
                float v = acc[mt][nt][i] + bv;
                if (EPI == 1)
                    v += ldx(resid, ((size_t)r_row0 + r) * N + c, rf32);
                if (EPI == 2) v = fmaxf(v, 0.0f);
                C[((size_t)c_row0 + r) * N + c] = f2bf(v);
            }
        }
    }
}

// QKV GEMM (tier C): N=3072 split epilogue on the 128x128 core.
__global__ __launch_bounds__(256, 2) void gemm_qkv(
    const void* __restrict__ A, long a_row0,
    const void* __restrict__ W, const void* __restrict__ bias,
    u16* __restrict__ Qo, u16* __restrict__ Ko, u16* __restrict__ Vt,
    const int* __restrict__ flags)
{
    GEMM_CORE(A, 1, a_row0, W, 0, 1024, 1024)
    if (n0 < 1024) {
#pragma unroll
        for (int mt = 0; mt < 4; mt++)
#pragma unroll
            for (int nt = 0; nt < 4; nt++) {
                const int c = ce0 + nt * 16;
                const float bv = ldx(bias, c, inf32);
#pragma unroll
                for (int i = 0; i < 4; i++) {
                    const int r = re0 + mt * 16 + i;
                    Qo[((size_t)a_row0 + r) * 1024 + c] =
                        f2bf((acc[mt][nt][i] + bv) * 0.125f);
                }
            }
    } else if (n0 < 2048) {
#pragma unroll
        for (int mt = 0; mt < 4; mt++)
#pragma unroll
            for (int nt = 0; nt < 4; nt++) {
                const int c = ce0 + nt * 16;
                const float bv = ldx(bias, c, inf32);
#pragma unroll
                for (int i = 0; i < 4; i++) {
                    const int r = re0 + mt * 16 + i;
                    Ko[(size_t)r * 1024 + (c - 1024)] = f2bf(acc[mt][nt][i] + bv);
                }
            }
    } else {
#pragma unroll
        for (int mt = 0; mt < 4; mt++)
#pragma unroll
            for (int nt = 0; nt < 4; nt++) {
                const int c = ce0 + nt * 16;
                const float bv = ldx(bias, c, inf32);
                const int cv = c - 2048;
                const int hh = cv >> 6, d = cv & 63;
                const int rb = re0 + mt * 16;
                const int bl = rb >> 10, t = rb & 1023;
                short4v pk;
#pragma unroll
                for (int i = 0; i < 4; i++)
                    pk[i] = (short)f2bf(acc[mt][nt][i] + bv);
                *(short4v*)&Vt[((size_t)(bl * 16 + hh) * 64 + d) * 1024 + t] = pk;
            }
    }
}

// fc2 K-chunk accumulating into fp32 (tier C only)
__global__ __launch_bounds__(256, 2) void gemm_accf32(
    const void* __restrict__ A, const void* __restrict__ W, long w_off,
    const void* __restrict__ bias, const u16* __restrict__ resid, long r_row0,
    float* __restrict__ C, int ldw, int init, const int* __restrict__ flags)
{
    GEMM_CORE(A, 0, 0, W, w_off, ldw, 1024)
#pragma unroll
    for (int mt = 0; mt < 4; mt++) {
#pragma unroll
        for (int nt = 0; nt < 4; nt++) {
            const int c = ce0 + nt * 16;
            const float bv = ldx(bias, c, inf32);
#pragma unroll
            for (int i = 0; i < 4; i++) {
                const int r = re0 + mt * 16 + i;
                float v = acc[mt][nt][i];
                if (init) v += bv + bf2f(resid[((size_t)r_row0 + r) * 1024 + c]);
                else      v += C[(size_t)r * 1024 + c];
                C[(size_t)r * 1024 + c] = v;
            }
        }
    }
}

// ---------------------------------------------------------------------------
// gemm8: 128x256 tile, BK=64, 512 threads = 8 waves (2M x 4N), per-wave 64x64.
// Triple-buffered, vmcnt(6). (retained for out-proj / fc2 where the 256-tile
// grid would leave half the device idle)
// ---------------------------------------------------------------------------
#define GEMM8_PRE(Ag_, Wg_, Kg_)                                              \
    __shared__ __align__(16) u16 Ab[3][128 * 64];                             \
    __shared__ __align__(16) u16 Bb[3][256 * 64];                             \
    const u16* Ag = (Ag_); const u16* Wg = (Wg_); const int Kg = (Kg_);       \
    const int tid  = threadIdx.x;                                             \
    const int lane = tid & 63;                                                \
    const int lc   = lane & 15;                                               \
    const int quad = lane >> 4;                                               \
    const int w    = tid >> 6;                                                \
    const int wr   = w >> 2;                                                  \
    const int wc   = w & 3;                                                   \
    const int m0 = blockIdx.x * 128;                                          \
    const int n0 = blockIdx.y * 256;                                          \
    const int srow = tid >> 3;                                                \
    const int scol = (((tid & 7) ^ (srow & 7)) << 3);                         \
    const int sw0 = (((quad) ^ (lc & 7)) << 3);                               \
    const int sw1 = sw0 ^ 32;                                                 \
    f32x4 acc[4][4] = {};                                                     \
    short8 af[4], bf[4];

#define SA8(buf, kk) do {                                                     \
    GLD16(Ag + (size_t)(m0 + srow) * Kg + (kk) + scol, &Ab[buf][tid * 8]);    \
    GLD16(Ag + (size_t)(m0 + 64 + srow) * Kg + (kk) + scol,                   \
          &Ab[buf][4096 + tid * 8]); } while (0)
#define SB8a(buf, kk) do {                                                    \
    GLD16(Wg + (size_t)(n0 + srow) * Kg + (kk) + scol, &Bb[buf][tid * 8]);    \
    GLD16(Wg + (size_t)(n0 + 64 + srow) * Kg + (kk) + scol,                   \
          &Bb[buf][4096 + tid * 8]); } while (0)
#define SB8b(buf, kk) do {                                                    \
    GLD16(Wg + (size_t)(n0 + 128 + srow) * Kg + (kk) + scol,                  \
          &Bb[buf][8192 + tid * 8]);                                          \
    GLD16(Wg + (size_t)(n0 + 192 + srow) * Kg + (kk) + scol,                  \
          &Bb[buf][12288 + tid * 8]); } while (0)
#define LDFR(rbuf, SW) do { _Pragma("unroll")                                 \
    for (int q_ = 0; q_ < 4; q_++) {                                          \
        af[q_] = *(const short8*)&Ab[rbuf][(wr * 64 + q_ * 16 + lc) * 64 + (SW)];\
        bf[q_] = *(const short8*)&Bb[rbuf][(wc * 64 + q_ * 16 + lc) * 64 + (SW)];\
    } } while (0)
#define MFMA16 do { _Pragma("unroll")                                         \
    for (int mq = 0; mq < 4; mq++) { _Pragma("unroll")                        \
    for (int nq = 0; nq < 4; nq++)                                            \
        acc[mq][nq] = __builtin_amdgcn_mfma_f32_16x16x32_bf16(                \
            af[mq], bf[nq], acc[mq][nq], 0, 0, 0); } } while (0)

#define GEMM8_LOOP                                                            \
    const int NT = Kg >> 6;                                                   \
    SA8(0, 0); SB8a(0, 0); SB8b(0, 0);                                        \
    if (NT > 1) { SA8(1, 64); SB8a(1, 64); SB8b(1, 64); }                     \
    if (NT > 1) asm volatile("s_waitcnt vmcnt(6)" ::: "memory");              \
    else        asm volatile("s_waitcnt vmcnt(0)" ::: "memory");              \
    __builtin_amdgcn_s_barrier();                                             \
    int rb_ = 0, wb_ = 2;                                                     \
    for (int t = 0; t < NT; ++t) {                                            \
        const bool s_ = (t + 2 < NT);                                         \
        const int k2_ = (t + 2) << 6;                                         \
        LDFR(rb_, sw0);                                                       \
        if (s_) { SA8(wb_, k2_); SB8a(wb_, k2_); }                            \
        __builtin_amdgcn_s_barrier();                                         \
        asm volatile("s_waitcnt lgkmcnt(0)" ::: "memory");                    \
        __builtin_amdgcn_s_setprio(1);                                        \
        MFMA16;                                                               \
        __builtin_amdgcn_s_setprio(0);                                        \
        __builtin_amdgcn_s_barrier();                                         \
        LDFR(rb_, sw1);                                                       \
        if (s_) SB8b(wb_, k2_);                                               \
        __builtin_amdgcn_s_barrier();                                         \
        asm volatile("s_waitcnt lgkmcnt(0)" ::: "memory");                    \
        __builtin_amdgcn_s_setprio(1);                                        \
        MFMA16;                                                               \
        __builtin_amdgcn_s_setprio(0);                                        \
        if (s_) asm volatile("s_waitcnt vmcnt(6)" ::: "memory");              \
        else    asm volatile("s_waitcnt vmcnt(0)" ::: "memory");              \
        __builtin_amdgcn_s_barrier();                                         \
        rb_ = (rb_ == 2) ? 0 : rb_ + 1;                                      \
        wb_ = (wb_ == 2) ? 0 : wb_ + 1;                                      \
    }                                                                         \
    const int cb0 = n0 + wc * 64 + lc;                                        \
    const int rb0 = m0 + wr * 64 + quad * 4;

// Generic: C = A @ W^T + bias (+resid EPI=1, relu EPI=2). All bf16.
template<int EPI>
__global__ __launch_bounds__(512, 2) void gemm8(
    const u16* __restrict__ A, const u16* __restrict__ W,
    const u16* __restrict__ bias, const u16* __restrict__ resid,
    u16* __restrict__ C, int N, int K)
{
    GEMM8_PRE(A, W, K)
    GEMM8_LOOP
#pragma unroll
    for (int mq = 0; mq < 4; mq++) {
#pragma unroll
        for (int nq = 0; nq < 4; nq++) {
            const int cN = cb0 + nq * 16;
            const float bv = bf2f(bias[cN]);
#pragma unroll
            for (int i = 0; i < 4; i++) {
                const int rM = rb0 + mq * 16 + i;
                float v = acc[mq][nq][i] + bv;
                if (EPI == 1) v += bf2f(resid[(size_t)rM * N + cN]);
                if (EPI == 2) v = fmaxf(v, 0.0f);
                C[(size_t)rM * N + cN] = f2bf(v);
            }
        }
    }
}

// ---------------------------------------------------------------------------
// gemm256: 256x256 tile, BK=32, 512 threads = 8 waves (2M x 4N), per-wave
// 128x64 (m201 geometry: 2.67 MFMA per ds_read_b128). Triple-buffered LDS
// (96 KiB): tile t reads buf t%3; tile t+2 staged during tile t. Per K-tile:
// 2 phases {ds_reads || stage 1 panel -> barrier -> lgkmcnt(0) -> setprio(1)
// -> 16 MFMA -> setprio(0) -> barrier}; end-of-tile vmcnt(4) leaves exactly
// tile t+2's 4 loads in flight (a full tile, >1300 cyc, to land).
// Swizzle (row stride = 64 B = 4 chunks): chunk ^= (row>>1)&3 on both the
// pre-swizzled global source (linear LDS dest) and the ds_read address.
// ---------------------------------------------------------------------------
#define GEMM256_PRE(Ag_, Wg_, Kg_)                                            \
    __shared__ __align__(16) u16 Ab[3][8192];                                 \
    __shared__ __align__(16) u16 Bb[3][8192];                                 \
    const u16* Ag = (Ag_); const u16* Wg = (Wg_); const int Kg = (Kg_);       \
    const int tid  = threadIdx.x;                                             \
    const int lane = tid & 63;                                                \
    const int lc   = lane & 15;                                               \
    const int quad = lane >> 4;                                               \
    const int w    = tid >> 6;                                                \
    const int wr   = w >> 2;                                                  \
    const int wc   = w & 3;                                                   \
    const int m0 = blockIdx.x * 256;                                          \
    const int n0 = blockIdx.y * 256;                                          \
    const int s_r = tid >> 2;                                                 \
    const int s_c = (((tid & 3) ^ ((tid >> 3) & 3)) << 3);                    \
    const int fsw = ((quad ^ ((lc >> 1) & 3)) << 3);                          \
    const int arow = wr * 128 + lc;                                           \
    const int brow = wc * 64 + lc;                                            \
    f32x4 acc[8][4] = {};                                                     \
    short8 af[4], bf[4];

#define SA256(buf, kk) do {                                                   \
    GLD16(Ag + (size_t)(m0 + s_r) * Kg + (kk) + s_c, &Ab[buf][tid * 8]);      \
    GLD16(Ag + (size_t)(m0 + 128 + s_r) * Kg + (kk) + s_c,                    \
          &Ab[buf][4096 + tid * 8]); } while (0)
#define SB256(buf, kk) do {                                                   \
    GLD16(Wg + (size_t)(n0 + s_r) * Kg + (kk) + s_c, &Bb[buf][tid * 8]);      \
    GLD16(Wg + (size_t)(n0 + 128 + s_r) * Kg + (kk) + s_c,                    \
          &Bb[buf][4096 + tid * 8]); } while (0)
#define LDA256(MH) do { _Pragma("unroll")                                     \
    for (int q_ = 0; q_ < 4; q_++)                                            \
        af[q_] = *(const short8*)                                             \
            &Ab[rb_][(arow + ((MH) * 4 + q_) * 16) * 32 + fsw]; } while (0)
#define LDB256 do { _Pragma("unroll")                                         \
    for (int q_ = 0; q_ < 4; q_++)                                            \
        bf[q_] = *(const short8*)                                             \
            &Bb[rb_][(brow + q_ * 16) * 32 + fsw]; } while (0)
#define MF256(MH) do { _Pragma("unroll")                                      \
    for (int mq = 0; mq < 4; mq++) { _Pragma("unroll")                        \
    for (int nq = 0; nq < 4; nq++)                                            \
        acc[(MH) * 4 + mq][nq] = __builtin_amdgcn_mfma_f32_16x16x32_bf16(     \
            af[mq], bf[nq], acc[(MH) * 4 + mq][nq], 0, 0, 0); } } while (0)

#define GEMM256_LOOP                                                          \
    const int NT = Kg >> 5;                                                   \
    SA256(0, 0); SB256(0, 0);                                                 \
    if (NT > 1) { SA256(1, 32); SB256(1, 32); }                               \
    if (NT > 1) asm volatile("s_waitcnt vmcnt(4)" ::: "memory");              \
    else        asm volatile("s_waitcnt vmcnt(0)" ::: "memory");              \
    __builtin_amdgcn_s_barrier();                                             \
    int rb_ = 0, wb_ = 2;                                                     \
    for (int t = 0; t < NT; ++t) {                                            \
        const bool s_ = (t + 2 < NT);                                         \
        const int k2_ = (t + 2) << 5;                                         \
        LDB256; LDA256(0);                                                    \
        if (s_) SA256(wb_, k2_);                                              \
        __builtin_amdgcn_s_barrier();                                         \
        asm volatile("s_waitcnt lgkmcnt(0)" ::: "memory");                    \
        __builtin_amdgcn_s_setprio(1);                                        \
        MF256(0);                                                             \
        __builtin_amdgcn_s_setprio(0);                                        \
        __builtin_amdgcn_s_barrier();                                         \
        LDA256(1);                                                            \
        if (s_) SB256(wb_, k2_);                                              \
        __builtin_amdgcn_s_barrier();                                         \
        asm volatile("s_waitcnt lgkmcnt(0)" ::: "memory");                    \
        __builtin_amdgcn_s_setprio(1);                                        \
        MF256(1);                                                             \
        __builtin_amdgcn_s_setprio(0);                                        \
        if (s_) asm volatile("s_waitcnt vmcnt(4)" ::: "memory");              \
        else    asm volatile("s_waitcnt vmcnt(0)" ::: "memory");              \
        __builtin_amdgcn_s_barrier();                                         \
        rb_ = (rb_ == 2) ? 0 : rb_ + 1;                                      \
        wb_ = (wb_ == 2) ? 0 : wb_ + 1;                                      \
    }                                                                         \
    const int cb0 = n0 + wc * 64 + lc;                                        \
    const int rb0 = m0 + wr * 128 + quad * 4;

// Generic 256-tile: C = A @ W^T + bias (+resid EPI=1, relu EPI=2). All bf16.
template<int EPI>
__global__ __launch_bounds__(512, 2) void gemm256(
    const u16* __restrict__ A, const u16* __restrict__ W,
    const u16* __restrict__ bias, const u16* __restrict__ resid,
    u16* __restrict__ C, int N, int K)
{
    GEMM256_PRE(A, W, K)
    GEMM256_LOOP
#pragma unroll
    for (int mq = 0; mq < 8; mq++) {
#pragma unroll
        for (int nq = 0; nq < 4; nq++) {
            const int cN = cb0 + nq * 16;
            const float bv = bf2f(bias[cN]);
#pragma unroll
            for (int i = 0; i < 4; i++) {
                const int rM = rb0 + mq * 16 + i;
                float v = acc[mq][nq][i] + bv;
                if (EPI == 1) v += bf2f(resid[(size_t)rM * N + cN]);
                if (EPI == 2) v = fmaxf(v, 0.0f);
                C[(size_t)rM * N + cN] = f2bf(v);
            }
        }
    }
}

// QKV on the gemm256 core (tier A): N=3072, K=1024. n0 block-uniform branch.
__global__ __launch_bounds__(512, 2) void gemm256_qkv(
    const u16* __restrict__ A, const u16* __restrict__ W,
    const u16* __restrict__ bias,
    u16* __restrict__ Qo, u16* __restrict__ Ko, u16* __restrict__ Vt)
{
    GEMM256_PRE(A, W, 1024)
    GEMM256_LOOP
    if (n0 < 1024) {
#pragma unroll
        for (int mq = 0; mq < 8; mq++)
#pragma unroll
            for (int nq = 0; nq < 4; nq++) {
                const int c = cb0 + nq * 16;
                const float bv = bf2f(bias[c]);
#pragma unroll
                for (int i = 0; i < 4; i++) {
                    const int r = rb0 + mq * 16 + i;
                    Qo[(size_t)r * 1024 + c] =
                        f2bf((acc[mq][nq][i] + bv) * 0.125f);
                }
            }
    } else if (n0 < 2048) {
#pragma unroll
        for (int mq = 0; mq < 8; mq++)
#pragma unroll
            for (int nq = 0; nq < 4; nq++) {
                const int c = cb0 + nq * 16;
                const float bv = bf2f(bias[c]);
#pragma unroll
                for (int i = 0; i < 4; i++) {
                    const int r = rb0 + mq * 16 + i;
                    Ko[(size_t)r * 1024 + (c - 1024)] =
                        f2bf(acc[mq][nq][i] + bv);
                }
            }
    } else {
#pragma unroll
        for (int mq = 0; mq < 8; mq++)
#pragma unroll
            for (int nq = 0; nq < 4; nq++) {
                const int c = cb0 + nq * 16;
                const float bv = bf2f(bias[c]);
                const int cv = c - 2048;
                const int hh = cv >> 6, d = cv & 63;
                const int rbase = rb0 + mq * 16;
                const int bl = rbase >> 10, tt = rbase & 1023;
                short4v pk;
#pragma unroll
                for (int i = 0; i < 4; i++)
                    pk[i] = (short)f2bf(acc[mq][nq][i] + bv);
                *(short4v*)&Vt[((size_t)(bl * 16 + hh) * 64 + d) * 1024 + tt] = pk;
            }
    }
}

// ---------------------------------------------------------------------------
// Flash attention v3: paired q-tiles (qt, 7-qt) of 128 rows -> uniform 18
// k-tile units/block. Double-buffered K/V staging. Grid (4, nbh).
// ---------------------------------------------------------------------------
__global__ __launch_bounds__(256, 2) void attn_kernel(
    u16* __restrict__ QO, const u16* __restrict__ Ko,
    const u16* __restrict__ Vt, const float* __restrict__ kb, int b0)
{
    __shared__ __align__(16) u16 Qs[2 * 128 * 32];   // [kcd][qrow][32]
    __shared__ __align__(16) u16 Ks[2][2 * 64 * 32]; // dbuf [kcd][key][32]
    __shared__ __align__(16) u16 Vs[2][2 * 64 * 32]; // dbuf [kck][d][32]
    __shared__ __align__(16) u16 Ps[4][32 * 72];
    __shared__ float kba[1024];

    const int tid  = threadIdx.x;
    const int lane = tid & 63;
    const int w    = tid >> 6;
    const int lc   = lane & 15;
    const int quad = lane >> 4;
    const int bl = blockIdx.y >> 4;
    const int h  = blockIdx.y & 15;
    const int b  = b0 + bl;

    // preload padding-bias column for this sequence
    *(f32x4*)&kba[tid * 4] = *(const f32x4*)&kb[b * 1024 + tid * 4];

    for (int p = 0; p < 2; p++) {
        const int qt = p ? 7 - (int)blockIdx.x : (int)blockIdx.x;

        // stage Q tile [kcd][128][32]
#pragma unroll
        for (int it = 0; it < 4; it++) {
            const int kcd = it >> 1, half = it & 1;
            const int r = half * 64 + (tid >> 2);
            const int c = kcd * 32 + (tid & 3) * 8;
            GLD16(&QO[((size_t)(b * 1024 + qt * 128 + r)) * 1024 + h * 64 + c],
                  &Qs[kcd * 4096 + half * 2048 + tid * 8]);
        }
        // stage kt=0 into buffer 0
        {
            const int rr = tid >> 2;
#pragma unroll
            for (int it = 0; it < 2; it++) {
                const int cc = it * 32 + (tid & 3) * 8;
                GLD16(&Ko[((size_t)(bl * 1024 + rr)) * 1024 + h * 64 + cc],
                      &Ks[0][it * 2048 + tid * 8]);
                GLD16(&Vt[((size_t)(bl * 16 + h) * 64 + rr) * 1024 + cc],
                      &Vs[0][it * 2048 + tid * 8]);
            }
        }
        __syncthreads();   // Q + K0/V0 (+ kba on p=0) ready

        short8 aq[2][2];
#pragma unroll
        for (int mt = 0; mt < 2; mt++)
#pragma unroll
            for (int kc = 0; kc < 2; kc++)
                aq[mt][kc] = *(const short8*)
                    &Qs[kc * 4096 + (w * 32 + mt * 16 + lc) * 32 + quad * 8];

        f32x4 o[2][4] = {};
        float m_i[2][4], l_i[2][4];
#pragma unroll
        for (int mt = 0; mt < 2; mt++)
#pragma unroll
            for (int i = 0; i < 4; i++) { m_i[mt][i] = -1e30f; l_i[mt][i] = 0.0f; }

        const int ktmax = 2 * qt + 2;
        for (int kt = 0; kt < ktmax; kt++) {
            const int cur = kt & 1;
            // prefetch kt+1 (overlaps with compute below; drained at barrier)
            if (kt + 1 < ktmax) {
                const int nxt = cur ^ 1;
                const int rr = tid >> 2;
#pragma unroll
                for (int it = 0; it < 2; it++) {
                    const int cc = it * 32 + (tid & 3) * 8;
                    GLD16(&Ko[((size_t)(bl * 1024 + (kt + 1) * 64 + rr)) * 1024 + h * 64 + cc],
                          &Ks[nxt][it * 2048 + tid * 8]);
                    GLD16(&Vt[((size_t)(bl * 16 + h) * 64 + rr) * 1024 + (kt + 1) * 64 + cc],
                          &Vs[nxt][it * 2048 + tid * 8]);
                }
            }

            // S = Q K^T
            short8 bk[4][2];
#pragma unroll
            for (int nt = 0; nt < 4; nt++)
#pragma unroll
                for (int kc = 0; kc < 2; kc++)
                    bk[nt][kc] = *(const short8*)
                        &Ks[cur][kc * 2048 + (nt * 16 + lc) * 32 + quad * 8];

            f32x4 s[2][4];
#pragma unroll
            for (int mt = 0; mt < 2; mt++)
#pragma unroll
                for (int nt = 0; nt < 4; nt++) {
                    f32x4 z = {};
#pragma unroll
                    for (int kc = 0; kc < 2; kc++)
                        z = __builtin_amdgcn_mfma_f32_16x16x32_bf16(
                            aq[mt][kc], bk[nt][kc], z, 0, 0, 0);
                    s[mt][nt] = z;
                }

            const int causal = (kt >= 2 * qt);   // block-uniform
            float al[2][4];
#pragma unroll
            for (int mt = 0; mt < 2; mt++) {
                const int qg0 = qt * 128 + w * 32 + mt * 16 + quad * 4;
#pragma unroll
                for (int nt = 0; nt < 4; nt++) {
                    const int kg = kt * 64 + nt * 16 + lc;
                    const float kbv = kba[kt * 64 + nt * 16 + lc];
#pragma unroll
                    for (int i = 0; i < 4; i++) {
                        float sv = s[mt][nt][i] + kbv;
                        if (causal && kg > qg0 + i) sv = -1e30f;
                        s[mt][nt][i] = sv;
                    }
                }
                float mnew[4], rs[4];
#pragma unroll
                for (int i = 0; i < 4; i++) {
                    float rm = fmaxf(fmaxf(s[mt][0][i], s[mt][1][i]),
                                     fmaxf(s[mt][2][i], s[mt][3][i]));
                    rm = fmaxf(rm, __shfl_xor(rm, 1));
                    rm = fmaxf(rm, __shfl_xor(rm, 2));
                    rm = fmaxf(rm, __shfl_xor(rm, 4));
                    rm = fmaxf(rm, __shfl_xor(rm, 8));
                    mnew[i] = fmaxf(m_i[mt][i], rm);
                    al[mt][i] = exp2f((m_i[mt][i] - mnew[i]) * 1.442695041f);
                    rs[i] = 0.0f;
                }
#pragma unroll
                for (int nt = 0; nt < 4; nt++)
#pragma unroll
                    for (int i = 0; i < 4; i++) {
                        float pp = exp2f((s[mt][nt][i] - mnew[i]) * 1.442695041f);
                        s[mt][nt][i] = pp;
                        rs[i] += pp;
                    }
#pragma unroll
                for (int i = 0; i < 4; i++) {
                    float r = rs[i];
                    r += __shfl_xor(r, 1);
                    r += __shfl_xor(r, 2);
                    r += __shfl_xor(r, 4);
                    r += __shfl_xor(r, 8);
                    l_i[mt][i] = l_i[mt][i] * al[mt][i] + r;
                    m_i[mt][i] = mnew[i];
                }
#pragma unroll
                for (int nt = 0; nt < 4; nt++)
#pragma unroll
                    for (int i = 0; i < 4; i++)
                        Ps[w][(mt * 16 + quad * 4 + i) * 72 + nt * 16 + lc] =
                            f2bf(s[mt][nt][i]);
            }

            // O = O*alpha + P @ V
            short8 ap[2][2], bv2[4][2];
#pragma unroll
            for (int mt = 0; mt < 2; mt++)
#pragma unroll
                for (int kc = 0; kc < 2; kc++)
                    ap[mt][kc] = *(const short8*)
                        &Ps[w][(mt * 16 + lc) * 72 + kc * 32 + quad * 8];
#pragma unroll
            for (int nt = 0; nt < 4; nt++)
#pragma unroll
                for (int kc = 0; kc < 2; kc++)
                    bv2[nt][kc] = *(const short8*)
                        &Vs[cur][kc * 2048 + (nt * 16 + lc) * 32 + quad * 8];
#pragma unroll
            for (int mt = 0; mt < 2; mt++)
#pragma unroll
                for (int nt = 0; nt < 4; nt++) {
                    f32x4 oo = o[mt][nt];
#pragma unroll
                    for (int i = 0; i < 4; i++) oo[i] *= al[mt][i];
#pragma unroll
                    for (int kc = 0; kc < 2; kc++)
                        oo = __builtin_amdgcn_mfma_f32_16x16x32_bf16(
                            ap[mt][kc], bv2[nt][kc], oo, 0, 0, 0);
                    o[mt][nt] = oo;
                }
            __syncthreads();   // prefetch drained; buffers safe to swap
        }

        // write O in place of Q (exclusive slice)
#pragma unroll
        for (int mt = 0; mt < 2; mt++)
#pragma unroll
            for (int i = 0; i < 4; i++) {
                const float inv = l_i[mt][i] > 0.0f ? 1.0f / l_i[mt][i] : 0.0f;
#pragma unroll
                for (int nt = 0; nt < 4; nt++) {
                    const int r = qt * 128 + w * 32 + mt * 16 + quad * 4 + i;
                    const int d = nt * 16 + lc;
                    QO[((size_t)(b * 1024 + r)) * 1024 + h * 64 + d] =
                        f2bf(o[mt][nt][i] * inv);
                }
            }
    }
}

// ---------------------------------------------------------------------------
// LayerNorm, one block/row, biased variance, eps=1e-12.
// ---------------------------------------------------------------------------
template<int IN16, int OUTSEL>
__global__ __launch_bounds__(256) void ln_kernel(
    const void* __restrict__ yv, const void* __restrict__ w,
    const void* __restrict__ bb, void* __restrict__ o, long o_row0,
    const int* __restrict__ flags)
{
    const int row = blockIdx.x;
    const int tid = threadIdx.x;
    const int inf32 = flags[0];
    float x0, x1, x2, x3;
    if (IN16) {
        const u16* p = (const u16*)yv + (size_t)row * 1024 + tid * 4;
        short4v v = *(const short4v*)p;
        x0 = bf2f((u16)v[0]); x1 = bf2f((u16)v[1]);
        x2 = bf2f((u16)v[2]); x3 = bf2f((u16)v[3]);
    } else {
        const float* p = (const float*)yv + (size_t)row * 1024 + tid * 4;
        f32x4 v = *(const f32x4*)p;
        x0 = v[0]; x1 = v[1]; x2 = v[2]; x3 = v[3];
    }
    float s = x0 + x1 + x2 + x3;
    float q = x0 * x0 + x1 * x1 + x2 * x2 + x3 * x3;
#pragma unroll
    for (int off = 32; off; off >>= 1) {
        s += __shfl_xor(s, off);
        q += __shfl_xor(q, off);
    }
    __shared__ float sm[8];
    const int lane = tid & 63, wv = tid >> 6;
    if (lane == 0) { sm[wv] = s; sm[4 + wv] = q; }
    __syncthreads();
    const float ts = sm[0] + sm[1] + sm[2] + sm[3];
    const float tq = sm[4] + sm[5] + sm[6] + sm[7];
    const float mean = ts * (1.0f / 1024.0f);
    float var = tq * (1.0f / 1024.0f) - mean * mean;
    if (var < 0.0f) var = 0.0f;
    const float rinv = rsqrtf(var + 1e-12f);

    const size_t obase = ((size_t)o_row0 + row) * 1024 + tid * 4;
#pragma unroll
    for (int j = 0; j < 4; j++) {
        const int c = tid * 4 + j;
        float xv = (j == 0) ? x0 : (j == 1) ? x1 : (j == 2) ? x2 : x3;
        float v = ldx(w, c, inf32) * ((xv - mean) * rinv) + ldx(bb, c, inf32);
        if (OUTSEL && inf32) ((float*)o)[obase + j] = v;
        else                 ((u16*)o)[obase + j] = f2bf(v);
    }
}

// ---------------------------------------------------------------------------
extern "C" void kernel_launch(void* const* d_in, const int* in_sizes, int n_in,
                              void* d_out, int out_size, void* d_ws, size_t ws_size,
                              hipStream_t stream)
{
    const void* x     = d_in[0];
    const void* in_w  = d_in[1];
    const void* in_b  = d_in[2];
    const void* out_w = d_in[3];
    const void* out_b = d_in[4];
    const void* fc1_w = d_in[5];
    const void* fc1_b = d_in[6];
    const void* fc2_w = d_in[7];
    const void* fc2_b = d_in[8];
    const void* ln1w  = d_in[9];
    const void* ln1b  = d_in[10];
    const void* ln2w  = d_in[11];
    const void* ln2b  = d_in[12];
    const void* pad   = d_in[13];
    u16* outp = (u16*)d_out;
    char* ws = (char*)d_ws;
    dim3 blk(256);
    dim3 blk8(512);

    const size_t MB = 1024 * 1024;
    const bool bigWS = ws_size >= (105 * MB + 64 * 1024);

    if (bigWS) {
        // Tier A layout:
        //  0-16  xb -> x1        16-22 w1b (dead after qkv) \
        //  22-24 wob (dead after proj)  24-32 f1b (dead after fc1) } -> y2 16-32
        //  32-40 f2b   40-41 biases     41-57 Ko    57-73 Vt
        //  73-89 y1    41-105 h (FF)    105+ flags / kbias
        u16*   xb   = (u16*)(ws + 0);
        u16*   x1   = (u16*)(ws + 0);
        u16*   w1b  = (u16*)(ws + 16 * MB);
        u16*   wob  = (u16*)(ws + 22 * MB);
        u16*   f1b  = (u16*)(ws + 24 * MB);
        u16*   f2b  = (u16*)(ws + 32 * MB);
        u16*   inbb = (u16*)(ws + 40 * MB);
        u16*   outbb= (u16*)(ws + 40 * MB + 8192);
        u16*   f1bb = (u16*)(ws + 40 * MB + 16384);
        u16*   f2bb = (u16*)(ws + 40 * MB + 24576);
        u16*   Ko   = (u16*)(ws + 41 * MB);
        u16*   Vt   = (u16*)(ws + 57 * MB);
        u16*   y1   = (u16*)(ws + 73 * MB);
        u16*   h    = (u16*)(ws + 41 * MB);
        u16*   y2   = (u16*)(ws + 16 * MB);
        int*   flags  = (int*)(ws + 105 * MB);
        int*   flagsA = (int*)(ws + 105 * MB + 32);
        float* kbias  = (float*)(ws + 105 * MB + 64);

        probe_kernel<<<dim3(1), dim3(64), 0, stream>>>(x, pad, flags, flagsA);
        mask_to_bias<<<dim3(32), blk, 0, stream>>>(pad, kbias, flags);
        conv4<<<dim3(8192), blk, 0, stream>>>(x, xb, 2097152, flags);
        conv4<<<dim3(3072), blk, 0, stream>>>(in_w, w1b, 786432, flags);
        conv4<<<dim3(1024), blk, 0, stream>>>(out_w, wob, 262144, flags);
        conv4<<<dim3(4096), blk, 0, stream>>>(fc1_w, f1b, 1048576, flags);
        conv4<<<dim3(4096), blk, 0, stream>>>(fc2_w, f2b, 1048576, flags);
        conv4<<<dim3(3), blk, 0, stream>>>(in_b, inbb, 768, flags);
        conv4<<<dim3(1), blk, 0, stream>>>(out_b, outbb, 256, flags);
        conv4<<<dim3(4), blk, 0, stream>>>(fc1_b, f1bb, 1024, flags);
        conv4<<<dim3(1), blk, 0, stream>>>(fc2_b, f2bb, 256, flags);

        // qkv on the gemm256 core: [8192,3072] K=1024
        gemm256_qkv<<<dim3(32, 12), blk8, 0, stream>>>(
            xb, w1b, inbb, outp, Ko, Vt);
        attn_kernel<<<dim3(4, 128), blk, 0, stream>>>(outp, Ko, Vt, kbias, 0);
        // out-proj: y1 = attn @ wob^T + outbb + xb   [8192,1024] K=1024
        gemm8<1><<<dim3(64, 4), blk8, 0, stream>>>(
            outp, wob, outbb, xb, y1, 1024, 1024);
        ln_kernel<1, 0><<<dim3(8192), blk, 0, stream>>>(y1, ln1w, ln1b, x1, 0, flags);
        // fc1: h = relu(x1 @ f1b^T + f1bb)   [8192,4096] K=1024
        gemm256<2><<<dim3(32, 16), blk8, 0, stream>>>(
            x1, f1b, f1bb, nullptr, h, 4096, 1024);
        // fc2: y2 = h @ f2b^T + f2bb + x1    [8192,1024] K=4096
        gemm8<1><<<dim3(64, 4), blk8, 0, stream>>>(
            h, f2b, f2bb, x1, y2, 1024, 4096);
        ln_kernel<1, 1><<<dim3(8192), blk, 0, stream>>>(y2, ln2w, ln2b, d_out, 0, flags);
    } else {
        // Tier C: quartered, 12.6 MB workspace
        u16*   Ko    = (u16*)(ws + 0);
        u16*   Vt    = (u16*)(ws + 4 * MB);
        u16*   y1h   = (u16*)(ws + 0);
        float* acc   = (float*)(ws + 0);
        u16*   hc    = (u16*)(ws + 8 * MB);
        int*   flags  = (int*)(ws + 12 * MB);
        int*   flagsA = (int*)(ws + 12 * MB + 32);
        float* kbias  = (float*)(ws + 12 * MB + 64);

        probe_kernel<<<dim3(1), dim3(64), 0, stream>>>(x, pad, flags, flagsA);
        mask_to_bias<<<dim3(32), blk, 0, stream>>>(pad, kbias, flags);

        for (int q = 0; q < 4; q++) {
            const long r0 = (long)q * 2048;
            gemm_qkv<<<dim3(16, 24), blk, 0, stream>>>(
                x, r0, in_w, in_b, outp, Ko, Vt, flags);
            attn_kernel<<<dim3(4, 32), blk, 0, stream>>>(
                outp, Ko, Vt, kbias, q * 2);
        }
        for (int hf = 0; hf < 2; hf++) {
            const long r0 = (long)hf * 4096;
            gemm_bt<1><<<dim3(32, 8), blk, 0, stream>>>(
                outp, 0, r0, out_w, 0, out_b, 0, x, 1, r0,
                y1h, 0, 1024, 1024, 1024, flags);
            ln_kernel<1, 0><<<dim3(4096), blk, 0, stream>>>(
                y1h, ln1w, ln1b, outp, r0, flags);
        }
        for (int q = 3; q >= 0; q--) {
            const long r0 = (long)q * 2048;
            for (int c = 0; c < 4; c++) {
                gemm_bt<2><<<dim3(16, 8), blk, 0, stream>>>(
                    outp, 0, r0, fc1_w, (long)c * 1024 * 1024, fc1_b, (long)c * 1024,
                    nullptr, 0, 0, hc, 0, 1024, 1024, 1024, flags);
                gemm_accf32<<<dim3(16, 8), blk, 0, stream>>>(
                    hc, fc2_w, (long)c * 1024, fc2_b, outp, r0,
                    acc, 4096, c == 0, flags);
            }
            ln_kernel<0, 1><<<dim3(2048), blk, 0, stream>>>(
                acc, ln2w, ln2b, d_out, r0, flags);
        }
    }
}

// Round 5
// 517.389 us; speedup vs baseline: 1.1813x; 1.0132x over previous
//
#include <hip/hip_runtime.h>

typedef unsigned short u16;
typedef __attribute__((ext_vector_type(8))) short short8;
typedef __attribute__((ext_vector_type(4))) short short4v;
typedef __attribute__((ext_vector_type(4))) float f32x4;

#define DEV static __device__ __forceinline__

DEV float bf2f(u16 h) {
    union { unsigned int u; float f; } v; v.u = ((unsigned int)h) << 16; return v.f;
}
DEV u16 f2bf(float f) {
    union { float f; unsigned int u; } v; v.f = f;
    unsigned int r = (v.u + 0x7fff + ((v.u >> 16) & 1)) >> 16;
    return (u16)r;
}
DEV float ldx(const void* p, size_t i, int f32) {
    return f32 ? ((const float*)p)[i] : bf2f(((const u16*)p)[i]);
}

// 0.125 (HD^-0.5) * log2(e): Q pre-scaled so attention softmax uses exp2 directly.
#define QSCL 0.18033688011112042f

#define GLD16(g, l) __builtin_amdgcn_global_load_lds( \
    (const __attribute__((address_space(1))) void*)(g), \
    (__attribute__((address_space(3))) void*)(l), 16, 0, 0)

#define STAGE(P, pf32, eoff, dst8) do {                                        \
    if (!(pf32)) { GLD16(((const u16*)(P)) + (eoff), (dst8)); }                \
    else {                                                                     \
        const float* _p = ((const float*)(P)) + (eoff);                        \
        f32x4 _a = *(const f32x4*)_p, _b = *(const f32x4*)(_p + 4);            \
        short8 _s;                                                             \
        _s[0]=(short)f2bf(_a[0]); _s[1]=(short)f2bf(_a[1]);                    \
        _s[2]=(short)f2bf(_a[2]); _s[3]=(short)f2bf(_a[3]);                    \
        _s[4]=(short)f2bf(_b[0]); _s[5]=(short)f2bf(_b[1]);                    \
        _s[6]=(short)f2bf(_b[2]); _s[7]=(short)f2bf(_b[3]);                    \
        *(short8*)(dst8) = _s;                                                 \
    } } while (0)

// ---------------------------------------------------------------------------
// Probe: flags[0]=1 -> inputs fp32; flags[1]=1 -> mask is bool bytes.
// ---------------------------------------------------------------------------
__global__ __launch_bounds__(64) void probe_kernel(
    const void* __restrict__ x, const void* __restrict__ pad,
    int* __restrict__ flags, int* __restrict__ flagsA)
{
    const int lane = threadIdx.x;
    const u16* xu = (const u16*)x;
    const unsigned int e = (xu[lane * 2] >> 7) & 0xFF;
    const int sane = (e >= 0x70 && e <= 0x8F) ? 1 : 0;
    unsigned long long m = __ballot(sane);
    const int f32 = (__popcll(m) < 32) ? 1 : 0;

    const unsigned int* pi = (const unsigned int*)pad;
    int bytes = 0;
#pragma unroll
    for (int j = 0; j < 6; j++) {
        unsigned int v = pi[128 + j * 64 + lane];
        if (v > 1u) bytes = 1;
    }
    m = __ballot(bytes);
    if (lane == 0) {
        flags[0] = f32; flags[1] = (m != 0ULL) ? 1 : 0;
        flagsA[0] = 0;  flagsA[1] = 0;
    }
}

__global__ __launch_bounds__(256) void conv4(
    const void* __restrict__ src, u16* __restrict__ dst, int n4,
    const int* __restrict__ flags)
{
    const int i = blockIdx.x * 256 + threadIdx.x;
    if (i >= n4) return;
    if (flags[0]) {
        f32x4 v = ((const f32x4*)src)[i];
        short4v s;
        s[0] = (short)f2bf(v[0]); s[1] = (short)f2bf(v[1]);
        s[2] = (short)f2bf(v[2]); s[3] = (short)f2bf(v[3]);
        ((short4v*)dst)[i] = s;
    } else {
        ((short4v*)dst)[i] = ((const short4v*)src)[i];
    }
}

__global__ __launch_bounds__(256) void mask_to_bias(
    const void* __restrict__ pad, float* __restrict__ out,
    const int* __restrict__ flags)
{
    const int i = blockIdx.x * 256 + threadIdx.x;
    const int mv = flags[1] ? (int)((const unsigned char*)pad)[i]
                            : ((const int*)pad)[i];
    out[i] = mv ? -1e30f : 0.0f;
}

// ---------------------------------------------------------------------------
// Shared GEMM core: 128x128 tile, BK=32, 256 threads (4 waves, 4x4 mfma each).
// (retained for tier C)
// ---------------------------------------------------------------------------
#define GEMM_CORE(Av, ASEL, a_row0, Wv, w_off, ldw, K)                        \
    __shared__ __align__(16) u16 As[128 * 32];                                \
    __shared__ __align__(16) u16 Bs[128 * 32];                                \
    const int inf32 = flags[0];                                               \
    const int af32  = (ASEL) ? inf32 : 0;                                     \
    const int tid  = threadIdx.x;                                             \
    const int lane = tid & 63;                                                \
    const int wave = tid >> 6;                                                \
    const int lc   = lane & 15;                                               \
    const int quad = lane >> 4;                                               \
    const int m0 = blockIdx.x * 128;                                          \
    const int n0 = blockIdx.y * 128;                                          \
    const int wm = (wave >> 1) * 64;                                          \
    const int wn = (wave & 1) * 64;                                           \
    const int r0 = tid >> 2;                                                  \
    const int ko = (tid & 3) * 8;                                             \
    f32x4 acc[4][4] = {};                                                     \
    for (int k0 = 0; k0 < (K); k0 += 32) {                                    \
        STAGE(Av, af32, ((size_t)(a_row0) + m0 + r0) * (K) + k0 + ko,         \
              &As[tid * 8]);                                                  \
        STAGE(Av, af32, ((size_t)(a_row0) + m0 + r0 + 64) * (K) + k0 + ko,    \
              &As[2048 + tid * 8]);                                           \
        STAGE(Wv, inf32, (size_t)(w_off) + (size_t)(n0 + r0) * (ldw) + k0 + ko,\
              &Bs[tid * 8]);                                                  \
        STAGE(Wv, inf32, (size_t)(w_off) + (size_t)(n0 + r0 + 64) * (ldw) + k0 + ko,\
              &Bs[2048 + tid * 8]);                                           \
        __syncthreads();                                                      \
        short8 afr[4], bfr[4];                                                \
        const int qd = quad * 8;                                              \
        _Pragma("unroll")                                                     \
        for (int mt = 0; mt < 4; mt++)                                        \
            afr[mt] = *(const short8*)&As[(wm + mt * 16 + lc) * 32 + qd];     \
        _Pragma("unroll")                                                     \
        for (int nt = 0; nt < 4; nt++)                                        \
            bfr[nt] = *(const short8*)&Bs[(wn + nt * 16 + lc) * 32 + qd];     \
        _Pragma("unroll")                                                     \
        for (int mt = 0; mt < 4; mt++)                                        \
            _Pragma("unroll")                                                 \
            for (int nt = 0; nt < 4; nt++)                                    \
                acc[mt][nt] = __builtin_amdgcn_mfma_f32_16x16x32_bf16(        \
                    afr[mt], bfr[nt], acc[mt][nt], 0, 0, 0);                  \
        __syncthreads();                                                      \
    }                                                                         \
    const int ce0 = n0 + wn + lc;                                             \
    const int re0 = m0 + wm + quad * 4;

// Generic GEMM: C = A @ W^T + bias.  EPI: 0 bias, 1 +resid, 2 +relu.
template<int EPI>
__global__ __launch_bounds__(256, 2) void gemm_bt(
    const void* __restrict__ A, int a_sel, long a_row0,
    const void* __restrict__ W, long w_off,
    const void* __restrict__ bias, long b_off,
    const void* __restrict__ resid, int r_sel, long r_row0,
    u16* __restrict__ C, long c_row0,
    int N, int K, int ldw, const int* __restrict__ flags)
{
    GEMM_CORE(A, a_sel, a_row0, W, w_off, ldw, K)
    const int rf32 = r_sel ? inf32 : 0;
#pragma unroll
    for (int mt = 0; mt < 4; mt++) {
#pragma unroll
        for (int nt = 0; nt < 4; nt++) {
            const int c = ce0 + nt * 16;
            const float bv = ldx(bias, (size_t)b_off + c, inf32);
#pragma unroll
            for (int i = 0; i < 4; i++) {
                const int r = re0 + mt * 16 + i;
                float v = acc[mt][nt][i] + bv;
                if (EPI == 1)
                    v += ldx(resid, ((size_t)r_row0 + r) * N + c, rf32);
                if (EPI == 2) v = fmaxf(v, 0.0f);
                C[((size_t)c_row0 + r) * N + c] = f2bf(v);
            }
        }
    }
}

// QKV GEMM (tier C): N=3072 split epilogue on the 128x128 core.
__global__ __launch_bounds__(256, 2) void gemm_qkv(
    const void* __restrict__ A, long a_row0,
    const void* __restrict__ W, const void* __restrict__ bias,
    u16* __restrict__ Qo, u16* __restrict__ Ko, u16* __restrict__ Vt,
    const int* __restrict__ flags)
{
    GEMM_CORE(A, 1, a_row0, W, 0, 1024, 1024)
    if (n0 < 1024) {
#pragma unroll
        for (int mt = 0; mt < 4; mt++)
#pragma unroll
            for (int nt = 0; nt < 4; nt++) {
                const int c = ce0 + nt * 16;
                const float bv = ldx(bias, c, inf32);
#pragma unroll
                for (int i = 0; i < 4; i++) {
                    const int r = re0 + mt * 16 + i;
                    Qo[((size_t)a_row0 + r) * 1024 + c] =
                        f2bf((acc[mt][nt][i] + bv) * QSCL);
                }
            }
    } else if (n0 < 2048) {
#pragma unroll
        for (int mt = 0; mt < 4; mt++)
#pragma unroll
            for (int nt = 0; nt < 4; nt++) {
                const int c = ce0 + nt * 16;
                const float bv = ldx(bias, c, inf32);
#pragma unroll
                for (int i = 0; i < 4; i++) {
                    const int r = re0 + mt * 16 + i;
                    Ko[(size_t)r * 1024 + (c - 1024)] = f2bf(acc[mt][nt][i] + bv);
                }
            }
    } else {
#pragma unroll
        for (int mt = 0; mt < 4; mt++)
#pragma unroll
            for (int nt = 0; nt < 4; nt++) {
                const int c = ce0 + nt * 16;
                const float bv = ldx(bias, c, inf32);
                const int cv = c - 2048;
                const int hh = cv >> 6, d = cv & 63;
                const int rb = re0 + mt * 16;
                const int bl = rb >> 10, t = rb & 1023;
                short4v pk;
#pragma unroll
                for (int i = 0; i < 4; i++)
                    pk[i] = (short)f2bf(acc[mt][nt][i] + bv);
                *(short4v*)&Vt[((size_t)(bl * 16 + hh) * 64 + d) * 1024 + t] = pk;
            }
    }
}

// fc2 K-chunk accumulating into fp32 (tier C only)
__global__ __launch_bounds__(256, 2) void gemm_accf32(
    const void* __restrict__ A, const void* __restrict__ W, long w_off,
    const void* __restrict__ bias, const u16* __restrict__ resid, long r_row0,
    float* __restrict__ C, int ldw, int init, const int* __restrict__ flags)
{
    GEMM_CORE(A, 0, 0, W, w_off, ldw, 1024)
#pragma unroll
    for (int mt = 0; mt < 4; mt++) {
#pragma unroll
        for (int nt = 0; nt < 4; nt++) {
            const int c = ce0 + nt * 16;
            const float bv = ldx(bias, c, inf32);
#pragma unroll
            for (int i = 0; i < 4; i++) {
                const int r = re0 + mt * 16 + i;
                float v = acc[mt][nt][i];
                if (init) v += bv + bf2f(resid[((size_t)r_row0 + r) * 1024 + c]);
                else      v += C[(size_t)r * 1024 + c];
                C[(size_t)r * 1024 + c] = v;
            }
        }
    }
}

// ---------------------------------------------------------------------------
// gemm8: 128x256 tile, BK=64, 512 threads = 8 waves (2M x 4N), per-wave 64x64.
// Triple-buffered, vmcnt(6). (retained for out-proj / fc2 where the 256-tile
// grid would leave half the device idle)
// ---------------------------------------------------------------------------
#define GEMM8_PRE(Ag_, Wg_, Kg_)                                              \
    __shared__ __align__(16) u16 Ab[3][128 * 64];                             \
    __shared__ __align__(16) u16 Bb[3][256 * 64];                             \
    const u16* Ag = (Ag_); const u16* Wg = (Wg_); const int Kg = (Kg_);       \
    const int tid  = threadIdx.x;                                             \
    const int lane = tid & 63;                                                \
    const int lc   = lane & 15;                                               \
    const int quad = lane >> 4;                                               \
    const int w    = tid >> 6;                                                \
    const int wr   = w >> 2;                                                  \
    const int wc   = w & 3;                                                   \
    const int m0 = blockIdx.x * 128;                                          \
    const int n0 = blockIdx.y * 256;                                          \
    const int srow = tid >> 3;                                                \
    const int scol = (((tid & 7) ^ (srow & 7)) << 3);                         \
    const int sw0 = (((quad) ^ (lc & 7)) << 3);                               \
    const int sw1 = sw0 ^ 32;                                                 \
    f32x4 acc[4][4] = {};                                                     \
    short8 af[4], bf[4];

#define SA8(buf, kk) do {                                                     \
    GLD16(Ag + (size_t)(m0 + srow) * Kg + (kk) + scol, &Ab[buf][tid * 8]);    \
    GLD16(Ag + (size_t)(m0 + 64 + srow) * Kg + (kk) + scol,                   \
          &Ab[buf][4096 + tid * 8]); } while (0)
#define SB8a(buf, kk) do {                                                    \
    GLD16(Wg + (size_t)(n0 + srow) * Kg + (kk) + scol, &Bb[buf][tid * 8]);    \
    GLD16(Wg + (size_t)(n0 + 64 + srow) * Kg + (kk) + scol,                   \
          &Bb[buf][4096 + tid * 8]); } while (0)
#define SB8b(buf, kk) do {                                                    \
    GLD16(Wg + (size_t)(n0 + 128 + srow) * Kg + (kk) + scol,                  \
          &Bb[buf][8192 + tid * 8]);                                          \
    GLD16(Wg + (size_t)(n0 + 192 + srow) * Kg + (kk) + scol,                  \
          &Bb[buf][12288 + tid * 8]); } while (0)
#define LDFR(rbuf, SW) do { _Pragma("unroll")                                 \
    for (int q_ = 0; q_ < 4; q_++) {                                          \
        af[q_] = *(const short8*)&Ab[rbuf][(wr * 64 + q_ * 16 + lc) * 64 + (SW)];\
        bf[q_] = *(const short8*)&Bb[rbuf][(wc * 64 + q_ * 16 + lc) * 64 + (SW)];\
    } } while (0)
#define MFMA16 do { _Pragma("unroll")                                         \
    for (int mq = 0; mq < 4; mq++) { _Pragma("unroll")                        \
    for (int nq = 0; nq < 4; nq++)                                            \
        acc[mq][nq] = __builtin_amdgcn_mfma_f32_16x16x32_bf16(                \
            af[mq], bf[nq], acc[mq][nq], 0, 0, 0); } } while (0)

#define GEMM8_LOOP                                                            \
    const int NT = Kg >> 6;                                                   \
    SA8(0, 0); SB8a(0, 0); SB8b(0, 0);                                        \
    if (NT > 1) { SA8(1, 64); SB8a(1, 64); SB8b(1, 64); }                     \
    if (NT > 1) asm volatile("s_waitcnt vmcnt(6)" ::: "memory");              \
    else        asm volatile("s_waitcnt vmcnt(0)" ::: "memory");              \
    __builtin_amdgcn_s_barrier();                                             \
    int rb_ = 0, wb_ = 2;                                                     \
    for (int t = 0; t < NT; ++t) {                                            \
        const bool s_ = (t + 2 < NT);                                         \
        const int k2_ = (t + 2) << 6;                                         \
        LDFR(rb_, sw0);                                                       \
        if (s_) { SA8(wb_, k2_); SB8a(wb_, k2_); }                            \
        __builtin_amdgcn_s_barrier();                                         \
        asm volatile("s_waitcnt lgkmcnt(0)" ::: "memory");                    \
        __builtin_amdgcn_s_setprio(1);                                        \
        MFMA16;                                                               \
        __builtin_amdgcn_s_setprio(0);                                        \
        __builtin_amdgcn_s_barrier();                                         \
        LDFR(rb_, sw1);                                                       \
        if (s_) SB8b(wb_, k2_);                                               \
        __builtin_amdgcn_s_barrier();                                         \
        asm volatile("s_waitcnt lgkmcnt(0)" ::: "memory");                    \
        __builtin_amdgcn_s_setprio(1);                                        \
        MFMA16;                                                               \
        __builtin_amdgcn_s_setprio(0);                                        \
        if (s_) asm volatile("s_waitcnt vmcnt(6)" ::: "memory");              \
        else    asm volatile("s_waitcnt vmcnt(0)" ::: "memory");              \
        __builtin_amdgcn_s_barrier();                                         \
        rb_ = (rb_ == 2) ? 0 : rb_ + 1;                                      \
        wb_ = (wb_ == 2) ? 0 : wb_ + 1;                                      \
    }                                                                         \
    const int cb0 = n0 + wc * 64 + lc;                                        \
    const int rb0 = m0 + wr * 64 + quad * 4;

// Generic: C = A @ W^T + bias (+resid EPI=1, relu EPI=2). All bf16.
template<int EPI>
__global__ __launch_bounds__(512, 2) void gemm8(
    const u16* __restrict__ A, const u16* __restrict__ W,
    const u16* __restrict__ bias, const u16* __restrict__ resid,
    u16* __restrict__ C, int N, int K)
{
    GEMM8_PRE(A, W, K)
    GEMM8_LOOP
#pragma unroll
    for (int mq = 0; mq < 4; mq++) {
#pragma unroll
        for (int nq = 0; nq < 4; nq++) {
            const int cN = cb0 + nq * 16;
            const float bv = bf2f(bias[cN]);
#pragma unroll
            for (int i = 0; i < 4; i++) {
                const int rM = rb0 + mq * 16 + i;
                float v = acc[mq][nq][i] + bv;
                if (EPI == 1) v += bf2f(resid[(size_t)rM * N + cN]);
                if (EPI == 2) v = fmaxf(v, 0.0f);
                C[(size_t)rM * N + cN] = f2bf(v);
            }
        }
    }
}

// ---------------------------------------------------------------------------
// gemm256: 256x256 tile, BK=32, 512 threads = 8 waves (2M x 4N), per-wave
// 128x64 (m201 geometry: 2.67 MFMA per ds_read_b128). Triple-buffered LDS
// (96 KiB). Per K-tile: 2 phases; end-of-tile vmcnt(4).
// ---------------------------------------------------------------------------
#define GEMM256_PRE(Ag_, Wg_, Kg_)                                            \
    __shared__ __align__(16) u16 Ab[3][8192];                                 \
    __shared__ __align__(16) u16 Bb[3][8192];                                 \
    const u16* Ag = (Ag_); const u16* Wg = (Wg_); const int Kg = (Kg_);       \
    const int tid  = threadIdx.x;                                             \
    const int lane = tid & 63;                                                \
    const int lc   = lane & 15;                                               \
    const int quad = lane >> 4;                                               \
    const int w    = tid >> 6;                                                \
    const int wr   = w >> 2;                                                  \
    const int wc   = w & 3;                                                   \
    const int m0 = blockIdx.x * 256;                                          \
    const int n0 = blockIdx.y * 256;                                          \
    const int s_r = tid >> 2;                                                 \
    const int s_c = (((tid & 3) ^ ((tid >> 3) & 3)) << 3);                    \
    const int fsw = ((quad ^ ((lc >> 1) & 3)) << 3);                          \
    const int arow = wr * 128 + lc;                                           \
    const int brow = wc * 64 + lc;                                            \
    f32x4 acc[8][4] = {};                                                     \
    short8 af[4], bf[4];

#define SA256(buf, kk) do {                                                   \
    GLD16(Ag + (size_t)(m0 + s_r) * Kg + (kk) + s_c, &Ab[buf][tid * 8]);      \
    GLD16(Ag + (size_t)(m0 + 128 + s_r) * Kg + (kk) + s_c,                    \
          &Ab[buf][4096 + tid * 8]); } while (0)
#define SB256(buf, kk) do {                                                   \
    GLD16(Wg + (size_t)(n0 + s_r) * Kg + (kk) + s_c, &Bb[buf][tid * 8]);      \
    GLD16(Wg + (size_t)(n0 + 128 + s_r) * Kg + (kk) + s_c,                    \
          &Bb[buf][4096 + tid * 8]); } while (0)
#define LDA256(MH) do { _Pragma("unroll")                                     \
    for (int q_ = 0; q_ < 4; q_++)                                            \
        af[q_] = *(const short8*)                                             \
            &Ab[rb_][(arow + ((MH) * 4 + q_) * 16) * 32 + fsw]; } while (0)
#define LDB256 do { _Pragma("unroll")                                         \
    for (int q_ = 0; q_ < 4; q_++)                                            \
        bf[q_] = *(const short8*)                                             \
            &Bb[rb_][(brow + q_ * 16) * 32 + fsw]; } while (0)
#define MF256(MH) do { _Pragma("unroll")                                      \
    for (int mq = 0; mq < 4; mq++) { _Pragma("unroll")                        \
    for (int nq = 0; nq < 4; nq++)                                            \
        acc[(MH) * 4 + mq][nq] = __builtin_amdgcn_mfma_f32_16x16x32_bf16(     \
            af[mq], bf[nq], acc[(MH) * 4 + mq][nq], 0, 0, 0); } } while (0)

#define GEMM256_LOOP                                                          \
    const int NT = Kg >> 5;                                                   \
    SA256(0, 0); SB256(0, 0);                                                 \
    if (NT > 1) { SA256(1, 32); SB256(1, 32); }                               \
    if (NT > 1) asm volatile("s_waitcnt vmcnt(4)" ::: "memory");              \
    else        asm volatile("s_waitcnt vmcnt(0)" ::: "memory");              \
    __builtin_amdgcn_s_barrier();                                             \
    int rb_ = 0, wb_ = 2;                                                     \
    for (int t = 0; t < NT; ++t) {                                            \
        const bool s_ = (t + 2 < NT);                                         \
        const int k2_ = (t + 2) << 5;                                         \
        LDB256; LDA256(0);                                                    \
        if (s_) SA256(wb_, k2_);                                              \
        __builtin_amdgcn_s_barrier();                                         \
        asm volatile("s_waitcnt lgkmcnt(0)" ::: "memory");                    \
        __builtin_amdgcn_s_setprio(1);                                        \
        MF256(0);                                                             \
        __builtin_amdgcn_s_setprio(0);                                        \
        __builtin_amdgcn_s_barrier();                                         \
        LDA256(1);                                                            \
        if (s_) SB256(wb_, k2_);                                              \
        __builtin_amdgcn_s_barrier();                                         \
        asm volatile("s_waitcnt lgkmcnt(0)" ::: "memory");                    \
        __builtin_amdgcn_s_setprio(1);                                        \
        MF256(1);                                                             \
        __builtin_amdgcn_s_setprio(0);                                        \
        if (s_) asm volatile("s_waitcnt vmcnt(4)" ::: "memory");              \
        else    asm volatile("s_waitcnt vmcnt(0)" ::: "memory");              \
        __builtin_amdgcn_s_barrier();                                         \
        rb_ = (rb_ == 2) ? 0 : rb_ + 1;                                      \
        wb_ = (wb_ == 2) ? 0 : wb_ + 1;                                      \
    }                                                                         \
    const int cb0 = n0 + wc * 64 + lc;                                        \
    const int rb0 = m0 + wr * 128 + quad * 4;

// Generic 256-tile: C = A @ W^T + bias (+resid EPI=1, relu EPI=2). All bf16.
template<int EPI>
__global__ __launch_bounds__(512, 2) void gemm256(
    const u16* __restrict__ A, const u16* __restrict__ W,
    const u16* __restrict__ bias, const u16* __restrict__ resid,
    u16* __restrict__ C, int N, int K)
{
    GEMM256_PRE(A, W, K)
    GEMM256_LOOP
#pragma unroll
    for (int mq = 0; mq < 8; mq++) {
#pragma unroll
        for (int nq = 0; nq < 4; nq++) {
            const int cN = cb0 + nq * 16;
            const float bv = bf2f(bias[cN]);
#pragma unroll
            for (int i = 0; i < 4; i++) {
                const int rM = rb0 + mq * 16 + i;
                float v = acc[mq][nq][i] + bv;
                if (EPI == 1) v += bf2f(resid[(size_t)rM * N + cN]);
                if (EPI == 2) v = fmaxf(v, 0.0f);
                C[(size_t)rM * N + cN] = f2bf(v);
            }
        }
    }
}

// QKV on the gemm256 core (tier A): N=3072, K=1024. n0 block-uniform branch.
__global__ __launch_bounds__(512, 2) void gemm256_qkv(
    const u16* __restrict__ A, const u16* __restrict__ W,
    const u16* __restrict__ bias,
    u16* __restrict__ Qo, u16* __restrict__ Ko, u16* __restrict__ Vt)
{
    GEMM256_PRE(A, W, 1024)
    GEMM256_LOOP
    if (n0 < 1024) {
#pragma unroll
        for (int mq = 0; mq < 8; mq++)
#pragma unroll
            for (int nq = 0; nq < 4; nq++) {
                const int c = cb0 + nq * 16;
                const float bv = bf2f(bias[c]);
#pragma unroll
                for (int i = 0; i < 4; i++) {
                    const int r = rb0 + mq * 16 + i;
                    Qo[(size_t)r * 1024 + c] =
                        f2bf((acc[mq][nq][i] + bv) * QSCL);
                }
            }
    } else if (n0 < 2048) {
#pragma unroll
        for (int mq = 0; mq < 8; mq++)
#pragma unroll
            for (int nq = 0; nq < 4; nq++) {
                const int c = cb0 + nq * 16;
                const float bv = bf2f(bias[c]);
#pragma unroll
                for (int i = 0; i < 4; i++) {
                    const int r = rb0 + mq * 16 + i;
                    Ko[(size_t)r * 1024 + (c - 1024)] =
                        f2bf(acc[mq][nq][i] + bv);
                }
            }
    } else {
#pragma unroll
        for (int mq = 0; mq < 8; mq++)
#pragma unroll
            for (int nq = 0; nq < 4; nq++) {
                const int c = cb0 + nq * 16;
                const float bv = bf2f(bias[c]);
                const int cv = c - 2048;
                const int hh = cv >> 6, d = cv & 63;
                const int rbase = rb0 + mq * 16;
                const int bl = rbase >> 10, tt = rbase & 1023;
                short4v pk;
#pragma unroll
                for (int i = 0; i < 4; i++)
                    pk[i] = (short)f2bf(acc[mq][nq][i] + bv);
                *(short4v*)&Vt[((size_t)(bl * 16 + hh) * 64 + d) * 1024 + tt] = pk;
            }
    }
}

// ---------------------------------------------------------------------------
// Flash attention v4: Q pre-scaled by log2e so softmax is exp2-native.
// VALU cuts vs v3: block-uniform causal branch; row-sum via MFMA against a
// constant ones-column B fragment (l kept in lc==0 lanes, broadcast at end);
// P->bf16 via v_cvt_pk_bf16_f32 pairs; O-rescale skipped when no new max
// (wave-uniform vote). Paired q-tiles (qt, 7-qt), dbuf K/V. Grid (4, nbh).
// ---------------------------------------------------------------------------
__global__ __launch_bounds__(256, 2) void attn_kernel(
    u16* __restrict__ QO, const u16* __restrict__ Ko,
    const u16* __restrict__ Vt, const float* __restrict__ kb, int b0)
{
    __shared__ __align__(16) u16 Qs[2 * 128 * 32];   // [kcd][qrow][32]
    __shared__ __align__(16) u16 Ks[2][2 * 64 * 32]; // dbuf [kcd][key][32]
    __shared__ __align__(16) u16 Vs[2][2 * 64 * 32]; // dbuf [kck][d][32]
    __shared__ __align__(16) u16 Ps[4][32 * 72];
    __shared__ float kba[1024];

    const int tid  = threadIdx.x;
    const int lane = tid & 63;
    const int w    = tid >> 6;
    const int lc   = lane & 15;
    const int quad = lane >> 4;
    const int bl = blockIdx.y >> 4;
    const int h  = blockIdx.y & 15;
    const int b  = b0 + bl;

    // constant B fragment: B[k][n] = (n==0) ? 1 : 0  ->  D[q][0] = sum_k P[q][k]
    short8 bsum;
    {
        const short ov = (lc == 0) ? (short)0x3F80 : (short)0;
#pragma unroll
        for (int j = 0; j < 8; j++) bsum[j] = ov;
    }

    // preload padding-bias column for this sequence
    *(f32x4*)&kba[tid * 4] = *(const f32x4*)&kb[b * 1024 + tid * 4];

    for (int p = 0; p < 2; p++) {
        const int qt = p ? 7 - (int)blockIdx.x : (int)blockIdx.x;

        // stage Q tile [kcd][128][32]
#pragma unroll
        for (int it = 0; it < 4; it++) {
            const int kcd = it >> 1, half = it & 1;
            const int r = half * 64 + (tid >> 2);
            const int c = kcd * 32 + (tid & 3) * 8;
            GLD16(&QO[((size_t)(b * 1024 + qt * 128 + r)) * 1024 + h * 64 + c],
                  &Qs[kcd * 4096 + half * 2048 + tid * 8]);
        }
        // stage kt=0 into buffer 0
        {
            const int rr = tid >> 2;
#pragma unroll
            for (int it = 0; it < 2; it++) {
                const int cc = it * 32 + (tid & 3) * 8;
                GLD16(&Ko[((size_t)(bl * 1024 + rr)) * 1024 + h * 64 + cc],
                      &Ks[0][it * 2048 + tid * 8]);
                GLD16(&Vt[((size_t)(bl * 16 + h) * 64 + rr) * 1024 + cc],
                      &Vs[0][it * 2048 + tid * 8]);
            }
        }
        __syncthreads();   // Q + K0/V0 (+ kba on p=0) ready

        short8 aq[2][2];
#pragma unroll
        for (int mt = 0; mt < 2; mt++)
#pragma unroll
            for (int kc = 0; kc < 2; kc++)
                aq[mt][kc] = *(const short8*)
                    &Qs[kc * 4096 + (w * 32 + mt * 16 + lc) * 32 + quad * 8];

        f32x4 o[2][4] = {};
        float m_i[2][4], l_i[2][4];
#pragma unroll
        for (int mt = 0; mt < 2; mt++)
#pragma unroll
            for (int i = 0; i < 4; i++) { m_i[mt][i] = -1e30f; l_i[mt][i] = 0.0f; }

        const int ktmax = 2 * qt + 2;
        for (int kt = 0; kt < ktmax; kt++) {
            const int cur = kt & 1;
            // prefetch kt+1 (overlaps with compute below; drained at barrier)
            if (kt + 1 < ktmax) {
                const int nxt = cur ^ 1;
                const int rr = tid >> 2;
#pragma unroll
                for (int it = 0; it < 2; it++) {
                    const int cc = it * 32 + (tid & 3) * 8;
                    GLD16(&Ko[((size_t)(bl * 1024 + (kt + 1) * 64 + rr)) * 1024 + h * 64 + cc],
                          &Ks[nxt][it * 2048 + tid * 8]);
                    GLD16(&Vt[((size_t)(bl * 16 + h) * 64 + rr) * 1024 + (kt + 1) * 64 + cc],
                          &Vs[nxt][it * 2048 + tid * 8]);
                }
            }

            // S = Q K^T  (already in log2 domain via Q pre-scale)
            short8 bk[4][2];
#pragma unroll
            for (int nt = 0; nt < 4; nt++)
#pragma unroll
                for (int kc = 0; kc < 2; kc++)
                    bk[nt][kc] = *(const short8*)
                        &Ks[cur][kc * 2048 + (nt * 16 + lc) * 32 + quad * 8];

            f32x4 s[2][4];
#pragma unroll
            for (int mt = 0; mt < 2; mt++)
#pragma unroll
                for (int nt = 0; nt < 4; nt++) {
                    f32x4 z = {};
#pragma unroll
                    for (int kc = 0; kc < 2; kc++)
                        z = __builtin_amdgcn_mfma_f32_16x16x32_bf16(
                            aq[mt][kc], bk[nt][kc], z, 0, 0, 0);
                    s[mt][nt] = z;
                }

            // padding bias (always) + causal mask (diagonal tiles only)
#pragma unroll
            for (int mt = 0; mt < 2; mt++)
#pragma unroll
                for (int nt = 0; nt < 4; nt++) {
                    const float kbv = kba[kt * 64 + nt * 16 + lc];
#pragma unroll
                    for (int i = 0; i < 4; i++) s[mt][nt][i] += kbv;
                }
            if (kt >= 2 * qt) {   // block-uniform branch
#pragma unroll
                for (int mt = 0; mt < 2; mt++) {
                    const int qg0 = qt * 128 + w * 32 + mt * 16 + quad * 4;
#pragma unroll
                    for (int nt = 0; nt < 4; nt++) {
                        const int kg = kt * 64 + nt * 16 + lc;
#pragma unroll
                        for (int i = 0; i < 4; i++)
                            if (kg > qg0 + i) s[mt][nt][i] = -1e30f;
                    }
                }
            }

            float al[2][4];
#pragma unroll
            for (int mt = 0; mt < 2; mt++) {
                float mnew[4];
#pragma unroll
                for (int i = 0; i < 4; i++) {
                    float rm = fmaxf(fmaxf(s[mt][0][i], s[mt][1][i]),
                                     fmaxf(s[mt][2][i], s[mt][3][i]));
                    rm = fmaxf(rm, __shfl_xor(rm, 1));
                    rm = fmaxf(rm, __shfl_xor(rm, 2));
                    rm = fmaxf(rm, __shfl_xor(rm, 4));
                    rm = fmaxf(rm, __shfl_xor(rm, 8));
                    const float mn = fmaxf(m_i[mt][i], rm);
                    al[mt][i] = exp2f(m_i[mt][i] - mn);
                    m_i[mt][i] = mn;
                    mnew[i] = mn;
                }
#pragma unroll
                for (int nt = 0; nt < 4; nt++)
#pragma unroll
                    for (int i = 0; i < 4; i++)
                        s[mt][nt][i] = exp2f(s[mt][nt][i] - mnew[i]);
                // P -> bf16 via packed cvt (rows quad*4+2j, quad*4+2j+1)
#pragma unroll
                for (int nt = 0; nt < 4; nt++) {
#pragma unroll
                    for (int i2 = 0; i2 < 2; i2++) {
                        unsigned int pk;
                        asm("v_cvt_pk_bf16_f32 %0, %1, %2"
                            : "=v"(pk)
                            : "v"(s[mt][nt][2 * i2]), "v"(s[mt][nt][2 * i2 + 1]));
                        Ps[w][(mt * 16 + quad * 4 + 2 * i2) * 72 + nt * 16 + lc] =
                            (u16)pk;
                        Ps[w][(mt * 16 + quad * 4 + 2 * i2 + 1) * 72 + nt * 16 + lc] =
                            (u16)(pk >> 16);
                    }
                }
            }
            int chg = 0;
#pragma unroll
            for (int mt = 0; mt < 2; mt++)
#pragma unroll
                for (int i = 0; i < 4; i++)
                    chg |= (al[mt][i] != 1.0f) ? 1 : 0;
            const int dor = __any(chg);   // wave-uniform

            // O = O*alpha + P @ V ; l-sum via MFMA against bsum
            short8 ap[2][2], bv2[4][2];
#pragma unroll
            for (int mt = 0; mt < 2; mt++)
#pragma unroll
                for (int kc = 0; kc < 2; kc++)
                    ap[mt][kc] = *(const short8*)
                        &Ps[w][(mt * 16 + lc) * 72 + kc * 32 + quad * 8];
#pragma unroll
            for (int nt = 0; nt < 4; nt++)
#pragma unroll
                for (int kc = 0; kc < 2; kc++)
                    bv2[nt][kc] = *(const short8*)
                        &Vs[cur][kc * 2048 + (nt * 16 + lc) * 32 + quad * 8];

            f32x4 ls[2] = {};
#pragma unroll
            for (int mt = 0; mt < 2; mt++)
#pragma unroll
                for (int kc = 0; kc < 2; kc++)
                    ls[mt] = __builtin_amdgcn_mfma_f32_16x16x32_bf16(
                        ap[mt][kc], bsum, ls[mt], 0, 0, 0);

#pragma unroll
            for (int mt = 0; mt < 2; mt++)
#pragma unroll
                for (int nt = 0; nt < 4; nt++) {
                    f32x4 oo = o[mt][nt];
                    if (dor) {
#pragma unroll
                        for (int i = 0; i < 4; i++) oo[i] *= al[mt][i];
                    }
#pragma unroll
                    for (int kc = 0; kc < 2; kc++)
                        oo = __builtin_amdgcn_mfma_f32_16x16x32_bf16(
                            ap[mt][kc], bv2[nt][kc], oo, 0, 0, 0);
                    o[mt][nt] = oo;
                }
#pragma unroll
            for (int mt = 0; mt < 2; mt++)
#pragma unroll
                for (int i = 0; i < 4; i++)
                    l_i[mt][i] = l_i[mt][i] * al[mt][i] + ls[mt][i];

            __syncthreads();   // prefetch drained; buffers safe to swap
        }

        // write O in place of Q (exclusive slice); true l lives in lc==0 lanes
#pragma unroll
        for (int mt = 0; mt < 2; mt++)
#pragma unroll
            for (int i = 0; i < 4; i++) {
                const float lv = __shfl(l_i[mt][i], (lane & 48));
                const float inv = lv > 0.0f ? 1.0f / lv : 0.0f;
#pragma unroll
                for (int nt = 0; nt < 4; nt++) {
                    const int r = qt * 128 + w * 32 + mt * 16 + quad * 4 + i;
                    const int d = nt * 16 + lc;
                    QO[((size_t)(b * 1024 + r)) * 1024 + h * 64 + d] =
                        f2bf(o[mt][nt][i] * inv);
                }
            }
    }
}

// ---------------------------------------------------------------------------
// LayerNorm, one block/row, biased variance, eps=1e-12.
// ---------------------------------------------------------------------------
template<int IN16, int OUTSEL>
__global__ __launch_bounds__(256) void ln_kernel(
    const void* __restrict__ yv, const void* __restrict__ w,
    const void* __restrict__ bb, void* __restrict__ o, long o_row0,
    const int* __restrict__ flags)
{
    const int row = blockIdx.x;
    const int tid = threadIdx.x;
    const int inf32 = flags[0];
    float x0, x1, x2, x3;
    if (IN16) {
        const u16* p = (const u16*)yv + (size_t)row * 1024 + tid * 4;
        short4v v = *(const short4v*)p;
        x0 = bf2f((u16)v[0]); x1 = bf2f((u16)v[1]);
        x2 = bf2f((u16)v[2]); x3 = bf2f((u16)v[3]);
    } else {
        const float* p = (const float*)yv + (size_t)row * 1024 + tid * 4;
        f32x4 v = *(const f32x4*)p;
        x0 = v[0]; x1 = v[1]; x2 = v[2]; x3 = v[3];
    }
    float s = x0 + x1 + x2 + x3;
    float q = x0 * x0 + x1 * x1 + x2 * x2 + x3 * x3;
#pragma unroll
    for (int off = 32; off; off >>= 1) {
        s += __shfl_xor(s, off);
        q += __shfl_xor(q, off);
    }
    __shared__ float sm[8];
    const int lane = tid & 63, wv = tid >> 6;
    if (lane == 0) { sm[wv] = s; sm[4 + wv] = q; }
    __syncthreads();
    const float ts = sm[0] + sm[1] + sm[2] + sm[3];
    const float tq = sm[4] + sm[5] + sm[6] + sm[7];
    const float mean = ts * (1.0f / 1024.0f);
    float var = tq * (1.0f / 1024.0f) - mean * mean;
    if (var < 0.0f) var = 0.0f;
    const float rinv = rsqrtf(var + 1e-12f);

    const size_t obase = ((size_t)o_row0 + row) * 1024 + tid * 4;
#pragma unroll
    for (int j = 0; j < 4; j++) {
        const int c = tid * 4 + j;
        float xv = (j == 0) ? x0 : (j == 1) ? x1 : (j == 2) ? x2 : x3;
        float v = ldx(w, c, inf32) * ((xv - mean) * rinv) + ldx(bb, c, inf32);
        if (OUTSEL && inf32) ((float*)o)[obase + j] = v;
        else                 ((u16*)o)[obase + j] = f2bf(v);
    }
}

// ---------------------------------------------------------------------------
extern "C" void kernel_launch(void* const* d_in, const int* in_sizes, int n_in,
                              void* d_out, int out_size, void* d_ws, size_t ws_size,
                              hipStream_t stream)
{
    const void* x     = d_in[0];
    const void* in_w  = d_in[1];
    const void* in_b  = d_in[2];
    const void* out_w = d_in[3];
    const void* out_b = d_in[4];
    const void* fc1_w = d_in[5];
    const void* fc1_b = d_in[6];
    const void* fc2_w = d_in[7];
    const void* fc2_b = d_in[8];
    const void* ln1w  = d_in[9];
    const void* ln1b  = d_in[10];
    const void* ln2w  = d_in[11];
    const void* ln2b  = d_in[12];
    const void* pad   = d_in[13];
    u16* outp = (u16*)d_out;
    char* ws = (char*)d_ws;
    dim3 blk(256);
    dim3 blk8(512);

    const size_t MB = 1024 * 1024;
    const bool bigWS = ws_size >= (105 * MB + 64 * 1024);

    if (bigWS) {
        // Tier A layout:
        //  0-16  xb -> x1        16-22 w1b (dead after qkv) \
        //  22-24 wob (dead after proj)  24-32 f1b (dead after fc1) } -> y2 16-32
        //  32-40 f2b   40-41 biases     41-57 Ko    57-73 Vt
        //  73-89 y1    41-105 h (FF)    105+ flags / kbias
        u16*   xb   = (u16*)(ws + 0);
        u16*   x1   = (u16*)(ws + 0);
        u16*   w1b  = (u16*)(ws + 16 * MB);
        u16*   wob  = (u16*)(ws + 22 * MB);
        u16*   f1b  = (u16*)(ws + 24 * MB);
        u16*   f2b  = (u16*)(ws + 32 * MB);
        u16*   inbb = (u16*)(ws + 40 * MB);
        u16*   outbb= (u16*)(ws + 40 * MB + 8192);
        u16*   f1bb = (u16*)(ws + 40 * MB + 16384);
        u16*   f2bb = (u16*)(ws + 40 * MB + 24576);
        u16*   Ko   = (u16*)(ws + 41 * MB);
        u16*   Vt   = (u16*)(ws + 57 * MB);
        u16*   y1   = (u16*)(ws + 73 * MB);
        u16*   h    = (u16*)(ws + 41 * MB);
        u16*   y2   = (u16*)(ws + 16 * MB);
        int*   flags  = (int*)(ws + 105 * MB);
        int*   flagsA = (int*)(ws + 105 * MB + 32);
        float* kbias  = (float*)(ws + 105 * MB + 64);

        probe_kernel<<<dim3(1), dim3(64), 0, stream>>>(x, pad, flags, flagsA);
        mask_to_bias<<<dim3(32), blk, 0, stream>>>(pad, kbias, flags);
        conv4<<<dim3(8192), blk, 0, stream>>>(x, xb, 2097152, flags);
        conv4<<<dim3(3072), blk, 0, stream>>>(in_w, w1b, 786432, flags);
        conv4<<<dim3(1024), blk, 0, stream>>>(out_w, wob, 262144, flags);
        conv4<<<dim3(4096), blk, 0, stream>>>(fc1_w, f1b, 1048576, flags);
        conv4<<<dim3(4096), blk, 0, stream>>>(fc2_w, f2b, 1048576, flags);
        conv4<<<dim3(3), blk, 0, stream>>>(in_b, inbb, 768, flags);
        conv4<<<dim3(1), blk, 0, stream>>>(out_b, outbb, 256, flags);
        conv4<<<dim3(4), blk, 0, stream>>>(fc1_b, f1bb, 1024, flags);
        conv4<<<dim3(1), blk, 0, stream>>>(fc2_b, f2bb, 256, flags);

        // qkv on the gemm256 core: [8192,3072] K=1024
        gemm256_qkv<<<dim3(32, 12), blk8, 0, stream>>>(
            xb, w1b, inbb, outp, Ko, Vt);
        attn_kernel<<<dim3(4, 128), blk, 0, stream>>>(outp, Ko, Vt, kbias, 0);
        // out-proj: y1 = attn @ wob^T + outbb + xb   [8192,1024] K=1024
        gemm8<1><<<dim3(64, 4), blk8, 0, stream>>>(
            outp, wob, outbb, xb, y1, 1024, 1024);
        ln_kernel<1, 0><<<dim3(8192), blk, 0, stream>>>(y1, ln1w, ln1b, x1, 0, flags);
        // fc1: h = relu(x1 @ f1b^T + f1bb)   [8192,4096] K=1024
        gemm256<2><<<dim3(32, 16), blk8, 0, stream>>>(
            x1, f1b, f1bb, nullptr, h, 4096, 1024);
        // fc2: y2 = h @ f2b^T + f2bb + x1    [8192,1024] K=4096
        gemm8<1><<<dim3(64, 4), blk8, 0, stream>>>(
            h, f2b, f2bb, x1, y2, 1024, 4096);
        ln_kernel<1, 1><<<dim3(8192), blk, 0, stream>>>(y2, ln2w, ln2b, d_out, 0, flags);
    } else {
        // Tier C: quartered, 12.6 MB workspace
        u16*   Ko    = (u16*)(ws + 0);
        u16*   Vt    = (u16*)(ws + 4 * MB);
        u16*   y1h   = (u16*)(ws + 0);
        float* acc   = (float*)(ws + 0);
        u16*   hc    = (u16*)(ws + 8 * MB);
        int*   flags  = (int*)(ws + 12 * MB);
        int*   flagsA = (int*)(ws + 12 * MB + 32);
        float* kbias  = (float*)(ws + 12 * MB + 64);

        probe_kernel<<<dim3(1), dim3(64), 0, stream>>>(x, pad, flags, flagsA);
        mask_to_bias<<<dim3(32), blk, 0, stream>>>(pad, kbias, flags);

        for (int q = 0; q < 4; q++) {
            const long r0 = (long)q * 2048;
            gemm_qkv<<<dim3(16, 24), blk, 0, stream>>>(
                x, r0, in_w, in_b, outp, Ko, Vt, flags);
            attn_kernel<<<dim3(4, 32), blk, 0, stream>>>(
                outp, Ko, Vt, kbias, q * 2);
        }
        for (int hf = 0; hf < 2; hf++) {
            const long r0 = (long)hf * 4096;
            gemm_bt<1><<<dim3(32, 8), blk, 0, stream>>>(
                outp, 0, r0, out_w, 0, out_b, 0, x, 1, r0,
                y1h, 0, 1024, 1024, 1024, flags);
            ln_kernel<1, 0><<<dim3(4096), blk, 0, stream>>>(
                y1h, ln1w, ln1b, outp, r0, flags);
        }
        for (int q = 3; q >= 0; q--) {
            const long r0 = (long)q * 2048;
            for (int c = 0; c < 4; c++) {
                gemm_bt<2><<<dim3(16, 8), blk, 0, stream>>>(
                    outp, 0, r0, fc1_w, (long)c * 1024 * 1024, fc1_b, (long)c * 1024,
                    nullptr, 0, 0, hc, 0, 1024, 1024, 1024, flags);
                gemm_accf32<<<dim3(16, 8), blk, 0, stream>>>(
                    hc, fc2_w, (long)c * 1024, fc2_b, outp, r0,
                    acc, 4096, c == 0, flags);
            }
            ln_kernel<0, 1><<<dim3(2048), blk, 0, stream>>>(
                acc, ln2w, ln2b, d_out, r0, flags);
        }
    }
}